// Round 6
// baseline (546.836 us; speedup 1.0000x reference)
//
#include <hip/hip_runtime.h>
#include <stdint.h>

// B=1, L=2048, DIM=1536, H=12, HD=128. Inputs f32, output f32 (verified R6).
// R13 post-mortem: counted-vmcnt retrofit on the 4-wave 128^2 2-phase loop =
// null (195us, MfmaUtil 18%) — exactly the guide's regime-gate: T3/T4/T5 pay
// only on the 8-wave 256-class multi-phase structure (m198/m201: 1167/1563 TF
// vs ~600 for 2-phase). R14 ports both GEMMs to that template, adapted to
// split-MFMA: 512 thr (8 waves 4Mx2N), BM=256 BN=128 BK=32; A pre-tiled
// (256-row tiles) -> global_load_lds into 3-deep LDS rotation; W split
// in-loop (1 split8v/thread/step) into 2-buf padded B; 4 dual-barrier phases
// per K-step; counted vmcnt(6) (never 0 in steady state); setprio around MFMA
// clusters. Accumulation order per element unchanged => bit-identical
// (absmax 3.428459e-3).
#define SEQ 2048
#define DIM 1536
#define NH  12
#define HD  128
#define SCALEF 0.08838834764831845f  // 128^-0.5

typedef __attribute__((ext_vector_type(8))) short short8;
typedef __attribute__((ext_vector_type(4))) float floatx4;

#define MFMA16(a, b, c) __builtin_amdgcn_mfma_f32_16x16x32_bf16((a), (b), (c), 0, 0, 0)

__device__ __forceinline__ void async_cp16(const void* g, void* l) {
  __builtin_amdgcn_global_load_lds(
      (__attribute__((address_space(1))) unsigned int*)(g),
      (__attribute__((address_space(3))) unsigned int*)(l), 16, 0, 0);
}

__device__ __forceinline__ unsigned short f2bf(float f) {
  unsigned int u = __float_as_uint(f);
  u = (u + 0x7fff + ((u >> 16) & 1)) >> 16;  // RNE
  return (unsigned short)u;
}

// Split f32 -> hi (truncated bf16) + lo (RNE bf16 of residual).
__device__ __forceinline__ void split8v(const float* x, short8& h, short8& l) {
#pragma unroll
  for (int e = 0; e < 8; e++) {
    unsigned int u = __float_as_uint(x[e]);
    h[e] = (short)(u >> 16);
    float r = x[e] - __uint_as_float(u & 0xFFFF0000u);
    l[e] = (short)f2bf(r);
  }
}
__device__ __forceinline__ void split8(const float* g, short8& h, short8& l) {
  float4 f0 = *(const float4*)g, f1 = *(const float4*)(g + 4);
  float x[8] = {f0.x, f0.y, f0.z, f0.w, f1.x, f1.y, f1.z, f1.w};
  split8v(x, h, l);
}

__global__ __launch_bounds__(256) void k_fill(float* __restrict__ out, int n,
                                              float val) {
  int i = blockIdx.x * 256 + threadIdx.x;
  if (i < n) out[i] = val;
}

// ---------------------------------------------------------------------------
// K0a: pre-split X -> tiled bf16 planes. Tile (mb2, ks) = 16KB/plane,
// rows mb2*256..+255 x k ks*32..+31, chunk-xor (p ^ (row>>1)&3) pre-applied
// so the GEMM's global_load_lds stream is linear. Grid: (48 ks, 8 mb2).
// ---------------------------------------------------------------------------
__global__ __launch_bounds__(256) void k_split_x(
    const float* __restrict__ X, unsigned short* __restrict__ Xh,
    unsigned short* __restrict__ Xl) {
  int ks = blockIdx.x, mb = blockIdx.y, tid = threadIdx.x;
  size_t tb = ((size_t)mb * 48 + ks) * 8192;
#pragma unroll
  for (int i = 0; i < 4; i++) {
    int sidx = i * 256 + tid;
    int row = sidx >> 2, p = sidx & 3;
    int c = p ^ ((row >> 1) & 3);
    short8 h, l;
    split8(X + (size_t)(mb * 256 + row) * DIM + ks * 32 + c * 8, h, l);
    *(short8*)(Xh + tb + sidx * 8) = h;
    *(short8*)(Xl + tb + sidx * 8) = l;
  }
}

// ---------------------------------------------------------------------------
// K0b: pre-sum + split attn output -> tiled Oh/Ol (same layout as k_split_x).
// ---------------------------------------------------------------------------
__global__ __launch_bounds__(256) void k_split_o(
    const float* __restrict__ A0, const float* __restrict__ A1,
    unsigned short* __restrict__ Oh, unsigned short* __restrict__ Ol) {
  int ks = blockIdx.x, mb = blockIdx.y, tid = threadIdx.x;
  size_t tb = ((size_t)mb * 48 + ks) * 8192;
#pragma unroll
  for (int i = 0; i < 4; i++) {
    int sidx = i * 256 + tid;
    int row = sidx >> 2, p = sidx & 3;
    int c = p ^ ((row >> 1) & 3);
    size_t off = (size_t)(mb * 256 + row) * DIM + ks * 32 + c * 8;
    float4 x0 = *(const float4*)(A0 + off), x1 = *(const float4*)(A0 + off + 4);
    float4 y0 = *(const float4*)(A1 + off), y1 = *(const float4*)(A1 + off + 4);
    float xs[8] = {x0.x + y0.x, x0.y + y0.y, x0.z + y0.z, x0.w + y0.w,
                   x1.x + y1.x, x1.y + y1.y, x1.z + y1.z, x1.w + y1.w};
    short8 h, l;
    split8v(xs, h, l);
    *(short8*)(Oh + tb + sidx * 8) = h;
    *(short8*)(Ol + tb + sidx * 8) = l;
  }
}

// ---------------------------------------------------------------------------
// Shared 8-wave multi-phase split-MFMA GEMM step. Needs in scope:
// Ah/Al (3x8192 LDS), Bh/Bl (2x5120 LDS), XH_, XL_, pB, tbase, tid, mrbase,
// nrbase, phA, q, rowB, c8, acc.
// ---------------------------------------------------------------------------
#define MFMA3(I, J, AH, AL, BH, BL)                \
  do {                                             \
    acc[I][J] = MFMA16(AH, BH, acc[I][J]);         \
    acc[I][J] = MFMA16(AH, BL, acc[I][J]);         \
    acc[I][J] = MFMA16(AL, BH, acc[I][J]);         \
  } while (0)

#define GSTEP(T, ACUR, BCUR, SP0, SP1, LD0, LD1, DO_STAGE, ENDWAIT)           \
  {                                                                           \
    const int t_ = (T);                                                       \
    const unsigned short* Ah_ = &Ah[0][0] + (ACUR) * 8192;                    \
    const unsigned short* Al_ = &Al[0][0] + (ACUR) * 8192;                    \
    const unsigned short* Bh_ = &Bh[0][0] + (BCUR) * 5120;                    \
    const unsigned short* Bl_ = &Bl[0][0] + (BCUR) * 5120;                    \
    unsigned short* BhN_ = &Bh[0][0] + ((BCUR) ^ 1) * 5120;                   \
    unsigned short* BlN_ = &Bl[0][0] + ((BCUR) ^ 1) * 5120;                   \
    /* P0: stage A(t+2), load W(t+2), read A0-1/B0-1, 12 MFMA */              \
    if (DO_STAGE) {                                                           \
      int sn_ = (ACUR) >= 1 ? (ACUR) - 1 : 2;                                 \
      size_t tn_ = tbase + (size_t)(t_ + 2) * 8192;                           \
      unsigned short* AhN_ = &Ah[0][0] + sn_ * 8192;                          \
      unsigned short* AlN_ = &Al[0][0] + sn_ * 8192;                          \
      async_cp16(XH_ + tn_ + tid * 8, AhN_ + tid * 8);                        \
      async_cp16(XH_ + tn_ + (512 + tid) * 8, AhN_ + (512 + tid) * 8);        \
      async_cp16(XL_ + tn_ + tid * 8, AlN_ + tid * 8);                        \
      async_cp16(XL_ + tn_ + (512 + tid) * 8, AlN_ + (512 + tid) * 8);        \
      int kn_ = (t_ + 2) * 32;                                                \
      LD0 = *(const float4*)(pB + kn_);                                       \
      LD1 = *(const float4*)(pB + kn_ + 4);                                   \
    }                                                                         \
    short8 a0h, a0l, a1h, a1l, a2h, a2l, a3h, a3l;                            \
    short8 b0h, b0l, b1h, b1l, b2h, b2l, b3h, b3l;                            \
    a0h = *(const short8*)(Ah_ + (mrbase + 0) * 32 + phA);                    \
    a0l = *(const short8*)(Al_ + (mrbase + 0) * 32 + phA);                    \
    a1h = *(const short8*)(Ah_ + (mrbase + 16) * 32 + phA);                   \
    a1l = *(const short8*)(Al_ + (mrbase + 16) * 32 + phA);                   \
    b0h = *(const short8*)(Bh_ + (nrbase + 0) * 40 + q * 8);                  \
    b0l = *(const short8*)(Bl_ + (nrbase + 0) * 40 + q * 8);                  \
    b1h = *(const short8*)(Bh_ + (nrbase + 16) * 40 + q * 8);                 \
    b1l = *(const short8*)(Bl_ + (nrbase + 16) * 40 + q * 8);                 \
    __builtin_amdgcn_s_barrier();                                             \
    asm volatile("s_waitcnt lgkmcnt(0)" ::: "memory");                        \
    __builtin_amdgcn_sched_barrier(0);                                        \
    __builtin_amdgcn_s_setprio(1);                                            \
    MFMA3(0, 0, a0h, a0l, b0h, b0l);                                          \
    MFMA3(0, 1, a0h, a0l, b1h, b1l);                                          \
    MFMA3(1, 0, a1h, a1l, b0h, b0l);                                          \
    MFMA3(1, 1, a1h, a1l, b1h, b1l);                                          \
    __builtin_amdgcn_s_setprio(0);                                            \
    __builtin_amdgcn_s_barrier();                                             \
    /* P1: read B2-3, split W(t+1) -> other B buf, 12 MFMA */                 \
    b2h = *(const short8*)(Bh_ + (nrbase + 32) * 40 + q * 8);                 \
    b2l = *(const short8*)(Bl_ + (nrbase + 32) * 40 + q * 8);                 \
    b3h = *(const short8*)(Bh_ + (nrbase + 48) * 40 + q * 8);                 \
    b3l = *(const short8*)(Bl_ + (nrbase + 48) * 40 + q * 8);                 \
    {                                                                         \
      float xs_[8] = {SP0.x, SP0.y, SP0.z, SP0.w,                             \
                      SP1.x, SP1.y, SP1.z, SP1.w};                            \
      short8 h_, l_;                                                          \
      split8v(xs_, h_, l_);                                                   \
      *(short8*)(BhN_ + rowB * 40 + c8 * 8) = h_;                             \
      *(short8*)(BlN_ + rowB * 40 + c8 * 8) = l_;                             \
    }                                                                         \
    __builtin_amdgcn_s_barrier();                                             \
    asm volatile("s_waitcnt lgkmcnt(2)" ::: "memory");                        \
    __builtin_amdgcn_sched_barrier(0);                                        \
    __builtin_amdgcn_s_setprio(1);                                            \
    MFMA3(0, 2, a0h, a0l, b2h, b2l);                                          \
    MFMA3(0, 3, a0h, a0l, b3h, b3l);                                          \
    MFMA3(1, 2, a1h, a1l, b2h, b2l);                                          \
    MFMA3(1, 3, a1h, a1l, b3h, b3l);                                          \
    __builtin_amdgcn_s_setprio(0);                                            \
    __builtin_amdgcn_s_barrier();                                             \
    /* P2: read A2-3, 12 MFMA */                                              \
    a2h = *(const short8*)(Ah_ + (mrbase + 32) * 32 + phA);                   \
    a2l = *(const short8*)(Al_ + (mrbase + 32) * 32 + phA);                   \
    a3h = *(const short8*)(Ah_ + (mrbase + 48) * 32 + phA);                   \
    a3l = *(const short8*)(Al_ + (mrbase + 48) * 32 + phA);                   \
    __builtin_amdgcn_s_barrier();                                             \
    asm volatile("s_waitcnt lgkmcnt(0)" ::: "memory");                        \
    __builtin_amdgcn_sched_barrier(0);                                        \
    __builtin_amdgcn_s_setprio(1);                                            \
    MFMA3(2, 0, a2h, a2l, b0h, b0l);                                          \
    MFMA3(2, 1, a2h, a2l, b1h, b1l);                                          \
    MFMA3(3, 0, a3h, a3l, b0h, b0l);                                          \
    MFMA3(3, 1, a3h, a3l, b1h, b1l);                                          \
    __builtin_amdgcn_s_setprio(0);                                            \
    __builtin_amdgcn_s_barrier();                                             \
    /* P3: 12 MFMA, counted-vmcnt end-of-step barrier */                      \
    __builtin_amdgcn_s_setprio(1);                                            \
    MFMA3(2, 2, a2h, a2l, b2h, b2l);                                          \
    MFMA3(2, 3, a2h, a2l, b3h, b3l);                                          \
    MFMA3(3, 2, a3h, a3l, b2h, b2l);                                          \
    MFMA3(3, 3, a3h, a3l, b3h, b3l);                                          \
    __builtin_amdgcn_s_setprio(0);                                            \
    asm volatile(ENDWAIT ::: "memory");                                       \
    __builtin_amdgcn_s_barrier();                                             \
    __builtin_amdgcn_sched_barrier(0);                                        \
  }

#define GFINAL(ACUR, BCUR)                                                    \
  {                                                                           \
    const unsigned short* Ah_ = &Ah[0][0] + (ACUR) * 8192;                    \
    const unsigned short* Al_ = &Al[0][0] + (ACUR) * 8192;                    \
    const unsigned short* Bh_ = &Bh[0][0] + (BCUR) * 5120;                    \
    const unsigned short* Bl_ = &Bl[0][0] + (BCUR) * 5120;                    \
    short8 ah_[4], al_[4], bh_[4], bl_[4];                                    \
    _Pragma("unroll") for (int i_ = 0; i_ < 4; i_++) {                        \
      ah_[i_] = *(const short8*)(Ah_ + (mrbase + i_ * 16) * 32 + phA);        \
      al_[i_] = *(const short8*)(Al_ + (mrbase + i_ * 16) * 32 + phA);        \
      bh_[i_] = *(const short8*)(Bh_ + (nrbase + i_ * 16) * 40 + q * 8);      \
      bl_[i_] = *(const short8*)(Bl_ + (nrbase + i_ * 16) * 40 + q * 8);      \
    }                                                                         \
    asm volatile("s_waitcnt lgkmcnt(0)" ::: "memory");                        \
    _Pragma("unroll") for (int i_ = 0; i_ < 4; i_++)                          \
      _Pragma("unroll") for (int j_ = 0; j_ < 4; j_++)                        \
        MFMA3(i_, j_, ah_[i_], al_[i_], bh_[j_], bl_[j_]);                    \
  }

#define GEMM_PRO()                                                            \
  {                                                                           \
    async_cp16(XH_ + tbase + tid * 8, &Ah[0][0] + tid * 8);                   \
    async_cp16(XH_ + tbase + (512 + tid) * 8, &Ah[0][0] + (512 + tid) * 8);   \
    async_cp16(XL_ + tbase + tid * 8, &Al[0][0] + tid * 8);                   \
    async_cp16(XL_ + tbase + (512 + tid) * 8, &Al[0][0] + (512 + tid) * 8);   \
    async_cp16(XH_ + tbase + 8192 + tid * 8, &Ah[1][0] + tid * 8);            \
    async_cp16(XH_ + tbase + 8192 + (512 + tid) * 8,                          \
               &Ah[1][0] + (512 + tid) * 8);                                  \
    async_cp16(XL_ + tbase + 8192 + tid * 8, &Al[1][0] + tid * 8);            \
    async_cp16(XL_ + tbase + 8192 + (512 + tid) * 8,                          \
               &Al[1][0] + (512 + tid) * 8);                                  \
    wB0 = *(const float4*)(pB);                                               \
    wB1 = *(const float4*)(pB + 4);                                           \
    wA0 = *(const float4*)(pB + 32);                                          \
    wA1 = *(const float4*)(pB + 36);                                          \
    float xs_[8] = {wB0.x, wB0.y, wB0.z, wB0.w, wB1.x, wB1.y, wB1.z, wB1.w};  \
    short8 h_, l_;                                                            \
    split8v(xs_, h_, l_);                                                     \
    *(short8*)(&Bh[0][0] + rowB * 40 + c8 * 8) = h_;                          \
    *(short8*)(&Bl[0][0] + rowB * 40 + c8 * 8) = l_;                          \
    asm volatile("s_waitcnt vmcnt(2) lgkmcnt(0)" ::: "memory");               \
    __builtin_amdgcn_s_barrier();                                             \
    __builtin_amdgcn_sched_barrier(0);                                        \
  }

#define GEMM_LOOP()                                                           \
  int acur = 0;                                                               \
  for (int p = 0; p < 23; ++p) {                                              \
    GSTEP(2 * p, acur, 0, wA0, wA1, wB0, wB1, 1,                              \
          "s_waitcnt vmcnt(6) lgkmcnt(0)");                                   \
    acur = (acur + 1 == 3) ? 0 : acur + 1;                                    \
    GSTEP(2 * p + 1, acur, 1, wB0, wB1, wA0, wA1, 1,                          \
          "s_waitcnt vmcnt(6) lgkmcnt(0)");                                   \
    acur = (acur + 1 == 3) ? 0 : acur + 1;                                    \
  }                                                                           \
  GSTEP(46, acur, 0, wA0, wA1, wB0, wB1, 0,                                   \
        "s_waitcnt vmcnt(0) lgkmcnt(0)");                                     \
  acur = (acur + 1 == 3) ? 0 : acur + 1;                                      \
  GFINAL(acur, 1);

// ---------------------------------------------------------------------------
// K1: QKV projections as one logical GEMM C[2048,4608]. 8 waves (4Mx2N),
// BM=256 BN=128 BK=32. Grid: 288 blocks (8 XCD x 36).
// ---------------------------------------------------------------------------
__global__ __launch_bounds__(512) void k_gemm_qkv(
    const unsigned short* __restrict__ Xh, const unsigned short* __restrict__ Xl,
    const float* __restrict__ Wq, const float* __restrict__ Wk,
    const float* __restrict__ Wv, float* __restrict__ qf,
    float* __restrict__ kf, float* __restrict__ vf,
    unsigned int* __restrict__ scal) {
  __shared__ __align__(16) unsigned short Ah[3][8192], Al[3][8192];
  __shared__ __align__(16) unsigned short Bh[2][5120], Bl[2][5120];
  int tid = threadIdx.x;
  int L = blockIdx.x;                      // 288 = 8 x 36 (bijective)
  int L2 = (L & 7) * 36 + (L >> 3);
  int by2 = L2 & 7, nIdx = L2 >> 3;        // nIdx 0..35
  int z = nIdx / 12, bx2 = nIdx % 12;
  const float* W = (z == 0) ? Wq : (z == 1) ? Wk : Wv;
  float* C = (z == 0) ? qf : (z == 1) ? kf : vf;
  int n0 = bx2 * 128, m0 = by2 * 256;
  int lane = tid & 63, w = tid >> 6;
  int wr = w >> 1, wc = w & 1, lm = lane & 15, q = lane >> 4;

  floatx4 acc[4][4];
#pragma unroll
  for (int i = 0; i < 4; i++)
#pragma unroll
    for (int j = 0; j < 4; j++) acc[i][j] = (floatx4){0.f, 0.f, 0.f, 0.f};

  int rowB = tid >> 2, c8 = tid & 3;
  const float* pB = W + (size_t)(n0 + rowB) * DIM + c8 * 8;
  size_t tbase = (size_t)by2 * 48 * 8192;
  int phA = (q ^ ((lm >> 1) & 3)) * 8;
  int mrbase = wr * 64 + lm;
  int nrbase = wc * 64 + lm;
  const unsigned short* XH_ = Xh;
  const unsigned short* XL_ = Xl;
  float4 wA0, wA1, wB0, wB1;

  GEMM_PRO();
  GEMM_LOOP();

  float am = 0.f;
#pragma unroll
  for (int i = 0; i < 4; i++) {
    int row = m0 + wr * 64 + i * 16 + q * 4;
#pragma unroll
    for (int j = 0; j < 4; j++) {
      int col = n0 + wc * 64 + j * 16 + lm;
#pragma unroll
      for (int r = 0; r < 4; r++) {
        float v = acc[i][j][r];
        C[(size_t)(row + r) * DIM + col] = v;
        am = fmaxf(am, fabsf(v));
      }
    }
  }
#pragma unroll
  for (int mk = 32; mk >= 1; mk >>= 1) am = fmaxf(am, __shfl_xor(am, mk, 64));
  if (lane == 0) atomicMax(&scal[z], __float_as_uint(am));
}

// ---------------------------------------------------------------------------
// K2a: quantize + transpose V -> nvT[h][d][k] (bf16 integer values).
// ---------------------------------------------------------------------------
__global__ __launch_bounds__(256) void k_quant_vT(
    const float* __restrict__ vf, const unsigned int* __restrict__ scal,
    unsigned short* __restrict__ nvT) {
  __shared__ float T[64 * 65];
  int h = blockIdx.z, d0 = blockIdx.y * 64, k0 = blockIdx.x * 64;
  float s = __uint_as_float(scal[2]) / 127.f;
  int t = threadIdx.x;
#pragma unroll
  for (int i = 0; i < 16; i++) {
    int idx = i * 256 + t;
    int r = idx >> 6, c = idx & 63;
    float v = vf[(size_t)(k0 + r) * DIM + h * HD + d0 + c];
    T[r * 65 + c] = fminf(fmaxf(rintf(v / s), -128.f), 127.f);
  }
  __syncthreads();
#pragma unroll
  for (int i = 0; i < 16; i++) {
    int idx = i * 256 + t;
    int d = idx >> 6, r = idx & 63;
    nvT[(size_t)(h * HD + d0 + d) * SEQ + k0 + r] = f2bf(T[r * 65 + d]);
  }
}

// ---------------------------------------------------------------------------
// K2b: quantize q,k -> integer-valued bf16.
// ---------------------------------------------------------------------------
__global__ __launch_bounds__(256) void k_quant_qk(
    const float* __restrict__ qf, const float* __restrict__ kf,
    const unsigned int* __restrict__ scal,
    unsigned short* __restrict__ nq, unsigned short* __restrict__ nk) {
  int z = blockIdx.y;
  const float* src = z ? kf : qf;
  unsigned short* dst = z ? nk : nq;
  float s = __uint_as_float(scal[z]) / 127.f;
  size_t i = ((size_t)blockIdx.x * 256 + threadIdx.x) * 4;
  float4 v = *(const float4*)(src + i);
  ushort4 o;
  o.x = f2bf(fminf(fmaxf(rintf(v.x / s), -128.f), 127.f));
  o.y = f2bf(fminf(fmaxf(rintf(v.y / s), -128.f), 127.f));
  o.z = f2bf(fminf(fmaxf(rintf(v.z / s), -128.f), 127.f));
  o.w = f2bf(fminf(fmaxf(rintf(v.w / s), -128.f), 127.f));
  *(ushort4*)(dst + i) = o;
}

// ---------------------------------------------------------------------------
// K3: partial softmax stats, split-K x8, online per-lane (m,z), swizzled Ks.
// Grid: (8*16, NH). pstats[h][row][chunk][2].
// ---------------------------------------------------------------------------
__global__ __launch_bounds__(256) void k_stats(
    const unsigned short* __restrict__ nq, const unsigned short* __restrict__ nk,
    const unsigned int* __restrict__ scal, float* __restrict__ pstats) {
  __shared__ unsigned short Ks[32 * 128];
  int h = blockIdx.y, tid = threadIdx.x, lane = tid & 63, w = tid >> 6;
  int lm = lane & 15, q = lane >> 4;
  int qb = blockIdx.x & 15, chunk = blockIdx.x >> 4;
  int mb = qb * 128 + w * 32;
  int kbase = chunk * 256;
  float f = (__uint_as_float(scal[0]) / 127.f) *
            (__uint_as_float(scal[1]) / 127.f) * SCALEF;

  short8 aq[2][4];
#pragma unroll
  for (int mi = 0; mi < 2; mi++) {
    const unsigned short* qb_p =
        nq + (size_t)(mb + mi * 16 + lm) * DIM + h * HD + q * 8;
#pragma unroll
    for (int cc = 0; cc < 4; cc++) aq[mi][cc] = *(const short8*)(qb_p + cc * 32);
  }

  float m[2][4], zz[2][4];
#pragma unroll
  for (int mi = 0; mi < 2; mi++)
#pragma unroll
    for (int r = 0; r < 4; r++) { m[mi][r] = -3.0e38f; zz[mi][r] = 0.f; }

  for (int kt = kbase; kt < kbase + 256; kt += 32) {
    __syncthreads();
#pragma unroll
    for (int i = 0; i < 2; i++) {
      int ch = i * 256 + tid;
      int krow = ch >> 4;
      int gcol = (ch & 15) ^ (krow & 7);  // xor-swizzle source column
      async_cp16(nk + (size_t)(kt + krow) * DIM + h * HD + gcol * 8,
                 Ks + ch * 8);
    }
    __syncthreads();
    short8 bk[2][4];
#pragma unroll
    for (int st = 0; st < 2; st++)
#pragma unroll
      for (int cc = 0; cc < 4; cc++) {
        int phys = (cc * 4 + q) ^ (lm & 7);
        bk[st][cc] = *(const short8*)(Ks + (st * 16 + lm) * 128 + phys * 8);
      }
#pragma unroll
    for (int mi = 0; mi < 2; mi++) {
      floatx4 a0 = (floatx4){0.f, 0.f, 0.f, 0.f};
      floatx4 a1 = (floatx4){0.f, 0.f, 0.f, 0.f};
#pragma unroll
      for (int cc = 0; cc < 4; cc++) {
        a0 = MFMA16(aq[mi][cc], bk[0][cc], a0);
        a1 = MFMA16(aq[mi][cc], bk[1][cc], a1);
      }
#pragma unroll
      for (int r = 0; r < 4; r++) {
        float s0 = a0[r] * f, s1 = a1[r] * f;
        float nm = fmaxf(m[mi][r], fmaxf(s0, s1));
        zz[mi][r] = zz[mi][r] * expf(m[mi][r] - nm) + expf(s0 - nm) +
                    expf(s1 - nm);
        m[mi][r] = nm;
      }
    }
  }
  // merge (m,z) across the 16 lanes sharing each row
#pragma unroll
  for (int mk = 1; mk < 16; mk <<= 1)
#pragma unroll
    for (int mi = 0; mi < 2; mi++)
#pragma unroll
      for (int r = 0; r < 4; r++) {
        float om = __shfl_xor(m[mi][r], mk, 64);
        float oz = __shfl_xor(zz[mi][r], mk, 64);
        float nm = fmaxf(m[mi][r], om);
        zz[mi][r] = zz[mi][r] * expf(m[mi][r] - nm) + oz * expf(om - nm);
        m[mi][r] = nm;
      }
  if (lm == 0) {
#pragma unroll
    for (int mi = 0; mi < 2; mi++)
#pragma unroll
      for (int r = 0; r < 4; r++) {
        int row = mb + mi * 16 + q * 4 + r;
        float* p = pstats + (((size_t)h * SEQ + row) * 8 + chunk) * 2;
        p[0] = m[mi][r];
        p[1] = zz[mi][r];
      }
  }
}

// ---------------------------------------------------------------------------
// K3b: merge 8 partial stats per row -> stats[h][row][2], global minZ.
// ---------------------------------------------------------------------------
__global__ __launch_bounds__(256) void k_merge(
    const float* __restrict__ pstats, float* __restrict__ stats,
    unsigned int* __restrict__ minZ) {
  int idx = blockIdx.x * 256 + threadIdx.x;  // h*SEQ + row
  const float* p = pstats + (size_t)idx * 16;
  float M = -3.0e38f;
#pragma unroll
  for (int c = 0; c < 8; c++) M = fmaxf(M, p[c * 2]);
  float Z = 0.f;
#pragma unroll
  for (int c = 0; c < 8; c++) Z += p[c * 2 + 1] * expf(p[c * 2] - M);
  stats[(size_t)idx * 2] = M;
  stats[(size_t)idx * 2 + 1] = Z;
  atomicMin(minZ, __float_as_uint(Z));
}

// ---------------------------------------------------------------------------
// K4: pass 2 — scores, quantize probs, PV. Split-K x2 -> partial O buffers.
// Grid: (2*16, NH). Swizzled Ks and Vs.
// ---------------------------------------------------------------------------
__global__ __launch_bounds__(256) void k_attn(
    const unsigned short* __restrict__ nq, const unsigned short* __restrict__ nk,
    const unsigned short* __restrict__ nvT,
    const unsigned int* __restrict__ scal, const unsigned int* __restrict__ minZ,
    const float* __restrict__ stats, float* __restrict__ attn0,
    float* __restrict__ attn1) {
  __shared__ unsigned short Ks[32 * 128];
  __shared__ unsigned short Vs[128 * 32];
  __shared__ unsigned short Pl[4][2][16 * 40];
  int h = blockIdx.y, tid = threadIdx.x, lane = tid & 63, w = tid >> 6;
  int lm = lane & 15, q = lane >> 4;
  int qb = blockIdx.x & 15, chunk = blockIdx.x >> 4;
  int mb = qb * 128 + w * 32;
  float* attn = chunk ? attn1 : attn0;
  float sv = __uint_as_float(scal[2]) / 127.f;
  float f = (__uint_as_float(scal[0]) / 127.f) *
            (__uint_as_float(scal[1]) / 127.f) * SCALEF;
  float sp = (1.f / __uint_as_float(*minZ)) / 127.f;
  float inv_sp = 1.f / sp;

  short8 aq[2][4];
#pragma unroll
  for (int mi = 0; mi < 2; mi++) {
    const unsigned short* qb_p =
        nq + (size_t)(mb + mi * 16 + lm) * DIM + h * HD + q * 8;
#pragma unroll
    for (int cc = 0; cc < 4; cc++) aq[mi][cc] = *(const short8*)(qb_p + cc * 32);
  }
  float M[2][4], invZ[2][4];
#pragma unroll
  for (int mi = 0; mi < 2; mi++)
#pragma unroll
    for (int r = 0; r < 4; r++) {
      int row = mb + mi * 16 + q * 4 + r;
      M[mi][r] = stats[((size_t)h * SEQ + row) * 2];
      invZ[mi][r] = 1.f / stats[((size_t)h * SEQ + row) * 2 + 1];
    }
  floatx4 accO[2][8];
#pragma unroll
  for (int mi = 0; mi < 2; mi++)
#pragma unroll
    for (int j = 0; j < 8; j++) accO[mi][j] = (floatx4){0.f, 0.f, 0.f, 0.f};

  int kbase = chunk * 1024;
  for (int kt = kbase; kt < kbase + 1024; kt += 32) {
    __syncthreads();
#pragma unroll
    for (int i = 0; i < 2; i++) {
      int ch = i * 256 + tid;
      int krow = ch >> 4;
      int gcol = (ch & 15) ^ (krow & 7);
      async_cp16(nk + (size_t)(kt + krow) * DIM + h * HD + gcol * 8,
                 Ks + ch * 8);
      int d = ch >> 2;
      int vcol = (ch & 3) ^ ((d >> 1) & 3);
      async_cp16(nvT + (size_t)(h * HD + d) * SEQ + kt + vcol * 8,
                 Vs + ch * 8);
    }
    __syncthreads();
    short8 bk[2][4];
#pragma unroll
    for (int st = 0; st < 2; st++)
#pragma unroll
      for (int cc = 0; cc < 4; cc++) {
        int phys = (cc * 4 + q) ^ (lm & 7);
        bk[st][cc] = *(const short8*)(Ks + (st * 16 + lm) * 128 + phys * 8);
      }
#pragma unroll
    for (int mi = 0; mi < 2; mi++)
#pragma unroll
      for (int st = 0; st < 2; st++) {
        floatx4 acc = (floatx4){0.f, 0.f, 0.f, 0.f};
#pragma unroll
        for (int cc = 0; cc < 4; cc++) acc = MFMA16(aq[mi][cc], bk[st][cc], acc);
#pragma unroll
        for (int r = 0; r < 4; r++) {
          float t = expf(acc[r] * f - M[mi][r]);
          float n = rintf(t * invZ[mi][r] * inv_sp);
          n = fminf(n, 127.f);
          Pl[w][mi][(q * 4 + r) * 40 + st * 16 + lm] = f2bf(n);
        }
      }
    __syncthreads();
    short8 ap[2];
#pragma unroll
    for (int mi = 0; mi < 2; mi++)
      ap[mi] = *(const short8*)(&Pl[w][mi][lm * 40 + q * 8]);
#pragma unroll
    for (int j = 0; j < 8; j++) {
      int d = j * 16 + lm;
      int vphys = q ^ ((d >> 1) & 3);
      short8 bv = *(const short8*)(Vs + d * 32 + vphys * 8);
#pragma unroll
      for (int mi = 0; mi < 2; mi++) accO[mi][j] = MFMA16(ap[mi], bv, accO[mi][j]);
    }
  }
  float osc = sp * sv;
#pragma unroll
  for (int mi = 0; mi < 2; mi++)
#pragma unroll
    for (int j = 0; j < 8; j++)
#pragma unroll
      for (int r = 0; r < 4; r++)
        attn[(size_t)(mb + mi * 16 + q * 4 + r) * DIM + h * HD + j * 16 + lm] =
            accO[mi][j][r] * osc;
}

// ---------------------------------------------------------------------------
// K5: out-proj: out[m,n] = sum_c O[m,c]*Wo[n,c] + bo[n]. Same 8-wave template.
// Grid: 96 blocks (8 XCD x 12).
// ---------------------------------------------------------------------------
__global__ __launch_bounds__(512) void k_gemm_out(
    const unsigned short* __restrict__ Oh, const unsigned short* __restrict__ Ol,
    const float* __restrict__ Wo, const float* __restrict__ bo,
    float* __restrict__ out) {
  __shared__ __align__(16) unsigned short Ah[3][8192], Al[3][8192];
  __shared__ __align__(16) unsigned short Bh[2][5120], Bl[2][5120];
  int tid = threadIdx.x;
  int L = blockIdx.x;                      // 96 = 8 x 12 (bijective)
  int L2 = (L & 7) * 12 + (L >> 3);
  int by2 = L2 & 7, bx2 = L2 >> 3;
  int n0 = bx2 * 128, m0 = by2 * 256;
  int lane = tid & 63, w = tid >> 6;
  int wr = w >> 1, wc = w & 1, lm = lane & 15, q = lane >> 4;

  floatx4 acc[4][4];
#pragma unroll
  for (int i = 0; i < 4; i++)
#pragma unroll
    for (int j = 0; j < 4; j++) acc[i][j] = (floatx4){0.f, 0.f, 0.f, 0.f};

  int rowB = tid >> 2, c8 = tid & 3;
  const float* pB = Wo + (size_t)(n0 + rowB) * DIM + c8 * 8;
  size_t tbase = (size_t)by2 * 48 * 8192;
  int phA = (q ^ ((lm >> 1) & 3)) * 8;
  int mrbase = wr * 64 + lm;
  int nrbase = wc * 64 + lm;
  const unsigned short* XH_ = Oh;
  const unsigned short* XL_ = Ol;
  float4 wA0, wA1, wB0, wB1;

  GEMM_PRO();
  GEMM_LOOP();

#pragma unroll
  for (int j = 0; j < 4; j++) {
    int col = n0 + wc * 64 + j * 16 + lm;
    float bias = bo[col];
#pragma unroll
    for (int i = 0; i < 4; i++) {
      int row = m0 + wr * 64 + i * 16 + q * 4;
#pragma unroll
      for (int r = 0; r < 4; r++)
        out[(size_t)(row + r) * DIM + col] = acc[i][j][r] + bias;
    }
  }
}

// ---------------------------------------------------------------------------
extern "C" void kernel_launch(void* const* d_in, const int* in_sizes, int n_in,
                              void* d_out, int out_size, void* d_ws, size_t ws_size,
                              hipStream_t stream) {
  float* out = (float*)d_out;
  bool sizes_ok = (n_in >= 6) && in_sizes && in_sizes[0] == SEQ * DIM &&
                  in_sizes[1] == DIM * DIM && in_sizes[2] == DIM * DIM &&
                  in_sizes[3] == DIM * DIM && in_sizes[4] == DIM * DIM &&
                  in_sizes[5] == DIM && out_size == SEQ * DIM;
  if (!sizes_ok) {
    k_fill<<<(out_size + 255) / 256, 256, 0, stream>>>(out, out_size, 1.0f);
    return;
  }
  if (ws_size < 50528272) {
    k_fill<<<(out_size + 255) / 256, 256, 0, stream>>>(out, out_size, 2.0f);
    return;
  }

  const float* x  = (const float*)d_in[0];
  const float* Wq = (const float*)d_in[1];
  const float* Wk = (const float*)d_in[2];
  const float* Wv = (const float*)d_in[3];
  const float* Wo = (const float*)d_in[4];
  const float* bo = (const float*)d_in[5];
  char* ws = (char*)d_ws;

  // Workspace layout (peak < 50.53 MB):
  float* qf = (float*)(ws);                                // 12,582,912 B
  float* kf = (float*)(ws + 12582912);                     // 12,582,912 B
  float* vf = (float*)(ws + 25165824);                     // 12,582,912 B
  unsigned short* nq  = (unsigned short*)(ws + 25165824);  // aliases vf (dead)
  float* pstats = (float*)(ws + 31457280);                 // 1,572,864 B
  unsigned short* nvT = (unsigned short*)(ws + 37748736);  // 6,291,456 B
  unsigned short* nk  = (unsigned short*)(ws + 44040192);  // 6,291,456 B
  // X-split tiled planes live in the nvT/nk slots until quant kernels run:
  unsigned short* Xh = nvT;   // dead after k_gemm_qkv
  unsigned short* Xl = nk;    // dead after k_gemm_qkv
  // attn-output tiled planes reuse the same slots after k_attn:
  unsigned short* Oh = nvT;   // written by k_split_o (nvT dead after k_attn)
  unsigned short* Ol = nk;    // written by k_split_o (nk dead after k_attn)
  float* attn0 = qf;                                       // aliases qf (dead)
  float* attn1 = kf;                                       // aliases kf (dead)
  float* stats = (float*)(ws + 50331648);                  // 196,608 B
  unsigned int* scal = (unsigned int*)(ws + 50528256);     // 16 B

  hipMemsetAsync(scal, 0, 12, stream);
  hipMemsetAsync(scal + 3, 0x7f, 4, stream);  // minZ init ~3.39e38

  k_split_x<<<dim3(48, 8), 256, 0, stream>>>(x, Xh, Xl);
  k_gemm_qkv<<<dim3(288), 512, 0, stream>>>(Xh, Xl, Wq, Wk, Wv, qf, kf, vf,
                                            scal);
  k_quant_vT<<<dim3(SEQ / 64, HD / 64, NH), 256, 0, stream>>>(vf, scal, nvT);
  k_quant_qk<<<dim3((SEQ * DIM) / 1024, 2), 256, 0, stream>>>(qf, kf, scal, nq, nk);
  k_stats<<<dim3(8 * 16, NH), 256, 0, stream>>>(nq, nk, scal, pstats);
  k_merge<<<dim3(NH * SEQ / 256), 256, 0, stream>>>(pstats, stats, scal + 3);
  k_attn<<<dim3(2 * 16, NH), 256, 0, stream>>>(nq, nk, nvT, scal, scal + 3,
                                               stats, attn0, attn1);
  k_split_o<<<dim3(48, 8), 256, 0, stream>>>(attn0, attn1, Oh, Ol);
  k_gemm_out<<<dim3(96), 512, 0, stream>>>(Oh, Ol, Wo, bo, out);
}

// Round 7
// 523.140 us; speedup vs baseline: 1.0453x; 1.0453x over previous
//
#include <hip/hip_runtime.h>
#include <stdint.h>

// B=1, L=2048, DIM=1536, H=12, HD=128. Inputs f32, output f32 (verified R6).
// R14 post-mortem: 8-wave multi-phase = 5th structural null on k_gemm_qkv
// (MfmaUtil pinned 17-18% across ALL schedules; VALUBusy 9-27% irrelevant),
// and 96-block k_gemm_out regressed total to 547. The wall is schedule-
// independent; per-kernel models underpredict the non-qkv ~320us by ~170us
// and those kernels have never appeared in top-5.
// R15: revert to R13 (best total 519.3us) + instrument: k_gemm_qkv split into
// two m-half dispatches (288 blocks each, same math/order => bit-identical)
// so the top-5 table exposes the three largest hidden dispatches.
#define SEQ 2048
#define DIM 1536
#define NH  12
#define HD  128
#define SCALEF 0.08838834764831845f  // 128^-0.5

typedef __attribute__((ext_vector_type(8))) short short8;
typedef __attribute__((ext_vector_type(4))) float floatx4;

#define MFMA16(a, b, c) __builtin_amdgcn_mfma_f32_16x16x32_bf16((a), (b), (c), 0, 0, 0)

__device__ __forceinline__ void async_cp16(const void* g, void* l) {
  __builtin_amdgcn_global_load_lds(
      (__attribute__((address_space(1))) unsigned int*)(g),
      (__attribute__((address_space(3))) unsigned int*)(l), 16, 0, 0);
}

__device__ __forceinline__ unsigned short f2bf(float f) {
  unsigned int u = __float_as_uint(f);
  u = (u + 0x7fff + ((u >> 16) & 1)) >> 16;  // RNE
  return (unsigned short)u;
}

// Split f32 -> hi (truncated bf16) + lo (RNE bf16 of residual).
__device__ __forceinline__ void split8v(const float* x, short8& h, short8& l) {
#pragma unroll
  for (int e = 0; e < 8; e++) {
    unsigned int u = __float_as_uint(x[e]);
    h[e] = (short)(u >> 16);
    float r = x[e] - __uint_as_float(u & 0xFFFF0000u);
    l[e] = (short)f2bf(r);
  }
}
__device__ __forceinline__ void split8(const float* g, short8& h, short8& l) {
  float4 f0 = *(const float4*)g, f1 = *(const float4*)(g + 4);
  float x[8] = {f0.x, f0.y, f0.z, f0.w, f1.x, f1.y, f1.z, f1.w};
  split8v(x, h, l);
}

__global__ __launch_bounds__(256) void k_fill(float* __restrict__ out, int n,
                                              float val) {
  int i = blockIdx.x * 256 + threadIdx.x;
  if (i < n) out[i] = val;
}

// ---------------------------------------------------------------------------
// K0a: pre-split X -> tiled bf16 planes. Tile (mb,ks) = 8KB contiguous,
// rows mb*128..+127 x k ks*32..+31, chunk-xor (p ^ (row>>1)&3) pre-applied.
// Grid: (48 ks, 16 mb).
// ---------------------------------------------------------------------------
__global__ __launch_bounds__(256) void k_split_x(
    const float* __restrict__ X, unsigned short* __restrict__ Xh,
    unsigned short* __restrict__ Xl) {
  int ks = blockIdx.x, mb = blockIdx.y, tid = threadIdx.x;
  size_t tb = ((size_t)mb * 48 + ks) * 4096;
#pragma unroll
  for (int i = 0; i < 2; i++) {
    int sidx = i * 256 + tid;
    int row = sidx >> 2, p = sidx & 3;
    int c = p ^ ((row >> 1) & 3);
    short8 h, l;
    split8(X + (size_t)(mb * 128 + row) * DIM + ks * 32 + c * 8, h, l);
    *(short8*)(Xh + tb + sidx * 8) = h;
    *(short8*)(Xl + tb + sidx * 8) = l;
  }
}

// ---------------------------------------------------------------------------
// K0b: pre-sum + split attn output -> tiled Oh/Ol (same layout as k_split_x).
// ---------------------------------------------------------------------------
__global__ __launch_bounds__(256) void k_split_o(
    const float* __restrict__ A0, const float* __restrict__ A1,
    unsigned short* __restrict__ Oh, unsigned short* __restrict__ Ol) {
  int ks = blockIdx.x, mb = blockIdx.y, tid = threadIdx.x;
  size_t tb = ((size_t)mb * 48 + ks) * 4096;
#pragma unroll
  for (int i = 0; i < 2; i++) {
    int sidx = i * 256 + tid;
    int row = sidx >> 2, p = sidx & 3;
    int c = p ^ ((row >> 1) & 3);
    size_t off = (size_t)(mb * 128 + row) * DIM + ks * 32 + c * 8;
    float4 x0 = *(const float4*)(A0 + off), x1 = *(const float4*)(A0 + off + 4);
    float4 y0 = *(const float4*)(A1 + off), y1 = *(const float4*)(A1 + off + 4);
    float xs[8] = {x0.x + y0.x, x0.y + y0.y, x0.z + y0.z, x0.w + y0.w,
                   x1.x + y1.x, x1.y + y1.y, x1.z + y1.z, x1.w + y1.w};
    short8 h, l;
    split8v(xs, h, l);
    *(short8*)(Oh + tb + sidx * 8) = h;
    *(short8*)(Ol + tb + sidx * 8) = l;
  }
}

// ---------------------------------------------------------------------------
// Pipelined split-MFMA GEMM step macros (shared by k_gemm_qkv / k_gemm_out).
// ---------------------------------------------------------------------------
#define COMPUTE_TILE(SA, SB)                                                  \
  {                                                                           \
    const unsigned short* Ah_ = Abh + (SA) * 4096;                            \
    const unsigned short* Al_ = Abl + (SA) * 4096;                            \
    const unsigned short* Bh_ = Bbh + (SB) * 4096;                            \
    const unsigned short* Bl_ = Bbl + (SB) * 4096;                            \
    short8 ah_[4], al_[4], bh_[4], bl_[4];                                    \
    _Pragma("unroll") for (int i_ = 0; i_ < 4; i_++) {                        \
      int off_ = (mrbase + i_ * 16) * 32 + phA;                               \
      ah_[i_] = *(const short8*)(Ah_ + off_);                                 \
      al_[i_] = *(const short8*)(Al_ + off_);                                 \
    }                                                                         \
    _Pragma("unroll") for (int j_ = 0; j_ < 4; j_++) {                        \
      int off_ = q * 1024 + (wc * 64 + j_ * 16 + lm) * 8;                     \
      bh_[j_] = *(const short8*)(Bh_ + off_);                                 \
      bl_[j_] = *(const short8*)(Bl_ + off_);                                 \
    }                                                                         \
    __builtin_amdgcn_s_setprio(1);                                            \
    _Pragma("unroll") for (int i_ = 0; i_ < 4; i_++)                          \
      _Pragma("unroll") for (int j_ = 0; j_ < 4; j_++) {                      \
        acc[i_][j_] = MFMA16(ah_[i_], bh_[j_], acc[i_][j_]);                  \
        acc[i_][j_] = MFMA16(ah_[i_], bl_[j_], acc[i_][j_]);                  \
        acc[i_][j_] = MFMA16(al_[i_], bh_[j_], acc[i_][j_]);                  \
      }                                                                       \
    __builtin_amdgcn_s_setprio(0);                                            \
  }

#define SPLIT_B(SB, S0x, S1x, S2x, S3x)                                       \
  {                                                                           \
    unsigned short* BhN_ = Bbh + (SB) * 4096;                                 \
    unsigned short* BlN_ = Bbl + (SB) * 4096;                                 \
    short8 h_, l_;                                                            \
    {                                                                         \
      float xs_[8] = {S0x.x, S0x.y, S0x.z, S0x.w,                             \
                      S1x.x, S1x.y, S1x.z, S1x.w};                            \
      split8v(xs_, h_, l_);                                                   \
      *(short8*)(BhN_ + c8 * 1024 + rowA * 8) = h_;                           \
      *(short8*)(BlN_ + c8 * 1024 + rowA * 8) = l_;                           \
    }                                                                         \
    {                                                                         \
      float xs_[8] = {S2x.x, S2x.y, S2x.z, S2x.w,                             \
                      S3x.x, S3x.y, S3x.z, S3x.w};                            \
      split8v(xs_, h_, l_);                                                   \
      *(short8*)(BhN_ + c8 * 1024 + (64 + rowA) * 8) = h_;                    \
      *(short8*)(BlN_ + c8 * 1024 + (64 + rowA) * 8) = l_;                    \
    }                                                                         \
  }

#define GSTEP(T, SCUR, S0x, S1x, S2x, S3x, L0x, L1x, L2x, L3x)                \
  {                                                                           \
    const int t_ = (T), sc_ = (SCUR);                                         \
    const int sn_ = sc_ >= 1 ? sc_ - 1 : 2; /* (sc_+2)%3 */                   \
    size_t tn_ = tb + (size_t)(t_ + 2) * 4096;                                \
    async_cp16(XH_ + tn_ + sidx0 * 8, Abh + sn_ * 4096 + sidx0 * 8);          \
    async_cp16(XL_ + tn_ + sidx0 * 8, Abl + sn_ * 4096 + sidx0 * 8);          \
    async_cp16(XH_ + tn_ + sidx1 * 8, Abh + sn_ * 4096 + sidx1 * 8);          \
    async_cp16(XL_ + tn_ + sidx1 * 8, Abl + sn_ * 4096 + sidx1 * 8);          \
    {                                                                         \
      int kn_ = (t_ + 2) * 32;                                                \
      L0x = *(const float4*)(pB0 + kn_);                                      \
      L1x = *(const float4*)(pB0 + kn_ + 4);                                  \
      L2x = *(const float4*)(pB1 + kn_);                                      \
      L3x = *(const float4*)(pB1 + kn_ + 4);                                  \
    }                                                                         \
    COMPUTE_TILE(sc_, (t_) & 1);                                              \
    SPLIT_B((t_ + 1) & 1, S0x, S1x, S2x, S3x);                                \
    asm volatile("s_waitcnt vmcnt(8) lgkmcnt(0)" ::: "memory");               \
    __builtin_amdgcn_s_barrier();                                             \
    __builtin_amdgcn_sched_barrier(0);                                        \
  }

// ---------------------------------------------------------------------------
// K1: QKV projections (m-half): C[m,n] = sum_c X[m,c]*W[n,c]. Split-MFMA,
// 128x128 tile, 3-deep A pipeline + W double-reg + counted vmcnt.
// Grid: (12, 8, 3) = 288 blocks per half; m_base selects the m-half.
// ---------------------------------------------------------------------------
__global__ __launch_bounds__(256) void k_gemm_qkv(
    const unsigned short* __restrict__ Xh, const unsigned short* __restrict__ Xl,
    const float* __restrict__ Wq, const float* __restrict__ Wk,
    const float* __restrict__ Wv, float* __restrict__ qf,
    float* __restrict__ kf, float* __restrict__ vf,
    unsigned int* __restrict__ scal, int m_base) {
  __shared__ __align__(16) unsigned short Ahs[3][4096], Als[3][4096];
  __shared__ __align__(16) unsigned short Bhs[2][4096], Bls[2][4096];
  int tid = threadIdx.x;
  // bijective XCD swizzle: 288 blocks = 8 XCDs x 36.
  int L = blockIdx.x + 12 * blockIdx.y + 96 * blockIdx.z;
  int L2 = (L & 7) * 36 + (L >> 3);
  int by2 = m_base + (L2 & 7);
  int rest = L2 >> 3;
  int bx2 = rest % 12, z = rest / 12;
  const float* W = (z == 0) ? Wq : (z == 1) ? Wk : Wv;
  float* C = (z == 0) ? qf : (z == 1) ? kf : vf;
  int n0 = bx2 * 128, m0 = by2 * 128;
  int lane = tid & 63, w = tid >> 6;
  int wr = w >> 1, wc = w & 1, lm = lane & 15, q = lane >> 4;

  floatx4 acc[4][4];
#pragma unroll
  for (int i = 0; i < 4; i++)
#pragma unroll
    for (int j = 0; j < 4; j++) acc[i][j] = (floatx4){0.f, 0.f, 0.f, 0.f};

  int rowA = tid >> 2, c8 = tid & 3;
  const float* pB0 = W + (size_t)(n0 + rowA) * DIM + c8 * 8;
  const float* pB1 = pB0 + (size_t)64 * DIM;
  size_t tb = (size_t)by2 * 48 * 4096;
  int sidx0 = tid, sidx1 = 256 + tid;
  int phA = (q ^ ((lm >> 1) & 3)) * 8;
  int mrbase = wr * 64 + lm;
  unsigned short* Abh = &Ahs[0][0];
  unsigned short* Abl = &Als[0][0];
  unsigned short* Bbh = &Bhs[0][0];
  unsigned short* Bbl = &Bls[0][0];
  const unsigned short* XH_ = Xh;
  const unsigned short* XL_ = Xl;

  float4 wA0, wA1, wA2, wA3, wB0, wB1, wB2, wB3;
  // prologue: W(0) -> wB (split now), A(0)->slot0, A(1)->slot1, W(1) -> wA.
  wB0 = *(const float4*)(pB0);
  wB1 = *(const float4*)(pB0 + 4);
  wB2 = *(const float4*)(pB1);
  wB3 = *(const float4*)(pB1 + 4);
  async_cp16(XH_ + tb + sidx0 * 8, Abh + sidx0 * 8);
  async_cp16(XL_ + tb + sidx0 * 8, Abl + sidx0 * 8);
  async_cp16(XH_ + tb + sidx1 * 8, Abh + sidx1 * 8);
  async_cp16(XL_ + tb + sidx1 * 8, Abl + sidx1 * 8);
  async_cp16(XH_ + tb + 4096 + sidx0 * 8, Abh + 4096 + sidx0 * 8);
  async_cp16(XL_ + tb + 4096 + sidx0 * 8, Abl + 4096 + sidx0 * 8);
  async_cp16(XH_ + tb + 4096 + sidx1 * 8, Abh + 4096 + sidx1 * 8);
  async_cp16(XL_ + tb + 4096 + sidx1 * 8, Abl + 4096 + sidx1 * 8);
  wA0 = *(const float4*)(pB0 + 32);
  wA1 = *(const float4*)(pB0 + 36);
  wA2 = *(const float4*)(pB1 + 32);
  wA3 = *(const float4*)(pB1 + 36);
  SPLIT_B(0, wB0, wB1, wB2, wB3);
  asm volatile("s_waitcnt vmcnt(8) lgkmcnt(0)" ::: "memory");
  __builtin_amdgcn_s_barrier();
  __builtin_amdgcn_sched_barrier(0);

  int scur = 0;
  for (int p = 0; p < 23; ++p) {
    GSTEP(2 * p, scur, wA0, wA1, wA2, wA3, wB0, wB1, wB2, wB3);
    scur = (scur + 1 == 3) ? 0 : scur + 1;
    GSTEP(2 * p + 1, scur, wB0, wB1, wB2, wB3, wA0, wA1, wA2, wA3);
    scur = (scur + 1 == 3) ? 0 : scur + 1;
  }
  // t=46: A slot 1, B slot 0; split W(47) (in wA) -> B slot 1.
  COMPUTE_TILE(1, 0);
  SPLIT_B(1, wA0, wA1, wA2, wA3);
  asm volatile("s_waitcnt lgkmcnt(0)" ::: "memory");
  __builtin_amdgcn_s_barrier();
  __builtin_amdgcn_sched_barrier(0);
  // t=47: A slot 2, B slot 1.
  COMPUTE_TILE(2, 1);

  float am = 0.f;
#pragma unroll
  for (int i = 0; i < 4; i++) {
    int row = m0 + wr * 64 + i * 16 + q * 4;
#pragma unroll
    for (int j = 0; j < 4; j++) {
      int col = n0 + wc * 64 + j * 16 + lm;
#pragma unroll
      for (int r = 0; r < 4; r++) {
        float v = acc[i][j][r];
        C[(size_t)(row + r) * DIM + col] = v;
        am = fmaxf(am, fabsf(v));
      }
    }
  }
#pragma unroll
  for (int mk = 32; mk >= 1; mk >>= 1) am = fmaxf(am, __shfl_xor(am, mk, 64));
  if (lane == 0) atomicMax(&scal[z], __float_as_uint(am));
}

// ---------------------------------------------------------------------------
// K2a: quantize + transpose V -> nvT[h][d][k] (bf16 integer values).
// ---------------------------------------------------------------------------
__global__ __launch_bounds__(256) void k_quant_vT(
    const float* __restrict__ vf, const unsigned int* __restrict__ scal,
    unsigned short* __restrict__ nvT) {
  __shared__ float T[64 * 65];
  int h = blockIdx.z, d0 = blockIdx.y * 64, k0 = blockIdx.x * 64;
  float s = __uint_as_float(scal[2]) / 127.f;
  int t = threadIdx.x;
#pragma unroll
  for (int i = 0; i < 16; i++) {
    int idx = i * 256 + t;
    int r = idx >> 6, c = idx & 63;
    float v = vf[(size_t)(k0 + r) * DIM + h * HD + d0 + c];
    T[r * 65 + c] = fminf(fmaxf(rintf(v / s), -128.f), 127.f);
  }
  __syncthreads();
#pragma unroll
  for (int i = 0; i < 16; i++) {
    int idx = i * 256 + t;
    int d = idx >> 6, r = idx & 63;
    nvT[(size_t)(h * HD + d0 + d) * SEQ + k0 + r] = f2bf(T[r * 65 + d]);
  }
}

// ---------------------------------------------------------------------------
// K2b: quantize q,k -> integer-valued bf16.
// ---------------------------------------------------------------------------
__global__ __launch_bounds__(256) void k_quant_qk(
    const float* __restrict__ qf, const float* __restrict__ kf,
    const unsigned int* __restrict__ scal,
    unsigned short* __restrict__ nq, unsigned short* __restrict__ nk) {
  int z = blockIdx.y;
  const float* src = z ? kf : qf;
  unsigned short* dst = z ? nk : nq;
  float s = __uint_as_float(scal[z]) / 127.f;
  size_t i = ((size_t)blockIdx.x * 256 + threadIdx.x) * 4;
  float4 v = *(const float4*)(src + i);
  ushort4 o;
  o.x = f2bf(fminf(fmaxf(rintf(v.x / s), -128.f), 127.f));
  o.y = f2bf(fminf(fmaxf(rintf(v.y / s), -128.f), 127.f));
  o.z = f2bf(fminf(fmaxf(rintf(v.z / s), -128.f), 127.f));
  o.w = f2bf(fminf(fmaxf(rintf(v.w / s), -128.f), 127.f));
  *(ushort4*)(dst + i) = o;
}

// ---------------------------------------------------------------------------
// K3: partial softmax stats, split-K x8, online per-lane (m,z), swizzled Ks.
// Grid: (8*16, NH). pstats[h][row][chunk][2].
// ---------------------------------------------------------------------------
__global__ __launch_bounds__(256) void k_stats(
    const unsigned short* __restrict__ nq, const unsigned short* __restrict__ nk,
    const unsigned int* __restrict__ scal, float* __restrict__ pstats) {
  __shared__ unsigned short Ks[32 * 128];
  int h = blockIdx.y, tid = threadIdx.x, lane = tid & 63, w = tid >> 6;
  int lm = lane & 15, q = lane >> 4;
  int qb = blockIdx.x & 15, chunk = blockIdx.x >> 4;
  int mb = qb * 128 + w * 32;
  int kbase = chunk * 256;
  float f = (__uint_as_float(scal[0]) / 127.f) *
            (__uint_as_float(scal[1]) / 127.f) * SCALEF;

  short8 aq[2][4];
#pragma unroll
  for (int mi = 0; mi < 2; mi++) {
    const unsigned short* qb_p =
        nq + (size_t)(mb + mi * 16 + lm) * DIM + h * HD + q * 8;
#pragma unroll
    for (int cc = 0; cc < 4; cc++) aq[mi][cc] = *(const short8*)(qb_p + cc * 32);
  }

  float m[2][4], zz[2][4];
#pragma unroll
  for (int mi = 0; mi < 2; mi++)
#pragma unroll
    for (int r = 0; r < 4; r++) { m[mi][r] = -3.0e38f; zz[mi][r] = 0.f; }

  for (int kt = kbase; kt < kbase + 256; kt += 32) {
    __syncthreads();
#pragma unroll
    for (int i = 0; i < 2; i++) {
      int ch = i * 256 + tid;
      int krow = ch >> 4;
      int gcol = (ch & 15) ^ (krow & 7);  // xor-swizzle source column
      async_cp16(nk + (size_t)(kt + krow) * DIM + h * HD + gcol * 8,
                 Ks + ch * 8);
    }
    __syncthreads();
    short8 bk[2][4];
#pragma unroll
    for (int st = 0; st < 2; st++)
#pragma unroll
      for (int cc = 0; cc < 4; cc++) {
        int phys = (cc * 4 + q) ^ (lm & 7);
        bk[st][cc] = *(const short8*)(Ks + (st * 16 + lm) * 128 + phys * 8);
      }
#pragma unroll
    for (int mi = 0; mi < 2; mi++) {
      floatx4 a0 = (floatx4){0.f, 0.f, 0.f, 0.f};
      floatx4 a1 = (floatx4){0.f, 0.f, 0.f, 0.f};
#pragma unroll
      for (int cc = 0; cc < 4; cc++) {
        a0 = MFMA16(aq[mi][cc], bk[0][cc], a0);
        a1 = MFMA16(aq[mi][cc], bk[1][cc], a1);
      }
#pragma unroll
      for (int r = 0; r < 4; r++) {
        float s0 = a0[r] * f, s1 = a1[r] * f;
        float nm = fmaxf(m[mi][r], fmaxf(s0, s1));
        zz[mi][r] = zz[mi][r] * expf(m[mi][r] - nm) + expf(s0 - nm) +
                    expf(s1 - nm);
        m[mi][r] = nm;
      }
    }
  }
  // merge (m,z) across the 16 lanes sharing each row
#pragma unroll
  for (int mk = 1; mk < 16; mk <<= 1)
#pragma unroll
    for (int mi = 0; mi < 2; mi++)
#pragma unroll
      for (int r = 0; r < 4; r++) {
        float om = __shfl_xor(m[mi][r], mk, 64);
        float oz = __shfl_xor(zz[mi][r], mk, 64);
        float nm = fmaxf(m[mi][r], om);
        zz[mi][r] = zz[mi][r] * expf(m[mi][r] - nm) + oz * expf(om - nm);
        m[mi][r] = nm;
      }
  if (lm == 0) {
#pragma unroll
    for (int mi = 0; mi < 2; mi++)
#pragma unroll
      for (int r = 0; r < 4; r++) {
        int row = mb + mi * 16 + q * 4 + r;
        float* p = pstats + (((size_t)h * SEQ + row) * 8 + chunk) * 2;
        p[0] = m[mi][r];
        p[1] = zz[mi][r];
      }
  }
}

// ---------------------------------------------------------------------------
// K3b: merge 8 partial stats per row -> stats[h][row][2], global minZ.
// ---------------------------------------------------------------------------
__global__ __launch_bounds__(256) void k_merge(
    const float* __restrict__ pstats, float* __restrict__ stats,
    unsigned int* __restrict__ minZ) {
  int idx = blockIdx.x * 256 + threadIdx.x;  // h*SEQ + row
  const float* p = pstats + (size_t)idx * 16;
  float M = -3.0e38f;
#pragma unroll
  for (int c = 0; c < 8; c++) M = fmaxf(M, p[c * 2]);
  float Z = 0.f;
#pragma unroll
  for (int c = 0; c < 8; c++) Z += p[c * 2 + 1] * expf(p[c * 2] - M);
  stats[(size_t)idx * 2] = M;
  stats[(size_t)idx * 2 + 1] = Z;
  atomicMin(minZ, __float_as_uint(Z));
}

// ---------------------------------------------------------------------------
// K4: pass 2 — scores, quantize probs, PV. Split-K x2 -> partial O buffers.
// Grid: (2*16, NH). Swizzled Ks and Vs.
// ---------------------------------------------------------------------------
__global__ __launch_bounds__(256) void k_attn(
    const unsigned short* __restrict__ nq, const unsigned short* __restrict__ nk,
    const unsigned short* __restrict__ nvT,
    const unsigned int* __restrict__ scal, const unsigned int* __restrict__ minZ,
    const float* __restrict__ stats, float* __restrict__ attn0,
    float* __restrict__ attn1) {
  __shared__ unsigned short Ks[32 * 128];
  __shared__ unsigned short Vs[128 * 32];
  __shared__ unsigned short Pl[4][2][16 * 40];
  int h = blockIdx.y, tid = threadIdx.x, lane = tid & 63, w = tid >> 6;
  int lm = lane & 15, q = lane >> 4;
  int qb = blockIdx.x & 15, chunk = blockIdx.x >> 4;
  int mb = qb * 128 + w * 32;
  float* attn = chunk ? attn1 : attn0;
  float sv = __uint_as_float(scal[2]) / 127.f;
  float f = (__uint_as_float(scal[0]) / 127.f) *
            (__uint_as_float(scal[1]) / 127.f) * SCALEF;
  float sp = (1.f / __uint_as_float(*minZ)) / 127.f;
  float inv_sp = 1.f / sp;

  short8 aq[2][4];
#pragma unroll
  for (int mi = 0; mi < 2; mi++) {
    const unsigned short* qb_p =
        nq + (size_t)(mb + mi * 16 + lm) * DIM + h * HD + q * 8;
#pragma unroll
    for (int cc = 0; cc < 4; cc++) aq[mi][cc] = *(const short8*)(qb_p + cc * 32);
  }
  float M[2][4], invZ[2][4];
#pragma unroll
  for (int mi = 0; mi < 2; mi++)
#pragma unroll
    for (int r = 0; r < 4; r++) {
      int row = mb + mi * 16 + q * 4 + r;
      M[mi][r] = stats[((size_t)h * SEQ + row) * 2];
      invZ[mi][r] = 1.f / stats[((size_t)h * SEQ + row) * 2 + 1];
    }
  floatx4 accO[2][8];
#pragma unroll
  for (int mi = 0; mi < 2; mi++)
#pragma unroll
    for (int j = 0; j < 8; j++) accO[mi][j] = (floatx4){0.f, 0.f, 0.f, 0.f};

  int kbase = chunk * 1024;
  for (int kt = kbase; kt < kbase + 1024; kt += 32) {
    __syncthreads();
#pragma unroll
    for (int i = 0; i < 2; i++) {
      int ch = i * 256 + tid;
      int krow = ch >> 4;
      int gcol = (ch & 15) ^ (krow & 7);
      async_cp16(nk + (size_t)(kt + krow) * DIM + h * HD + gcol * 8,
                 Ks + ch * 8);
      int d = ch >> 2;
      int vcol = (ch & 3) ^ ((d >> 1) & 3);
      async_cp16(nvT + (size_t)(h * HD + d) * SEQ + kt + vcol * 8,
                 Vs + ch * 8);
    }
    __syncthreads();
    short8 bk[2][4];
#pragma unroll
    for (int st = 0; st < 2; st++)
#pragma unroll
      for (int cc = 0; cc < 4; cc++) {
        int phys = (cc * 4 + q) ^ (lm & 7);
        bk[st][cc] = *(const short8*)(Ks + (st * 16 + lm) * 128 + phys * 8);
      }
#pragma unroll
    for (int mi = 0; mi < 2; mi++)
#pragma unroll
      for (int st = 0; st < 2; st++) {
        floatx4 acc = (floatx4){0.f, 0.f, 0.f, 0.f};
#pragma unroll
        for (int cc = 0; cc < 4; cc++) acc = MFMA16(aq[mi][cc], bk[st][cc], acc);
#pragma unroll
        for (int r = 0; r < 4; r++) {
          float t = expf(acc[r] * f - M[mi][r]);
          float n = rintf(t * invZ[mi][r] * inv_sp);
          n = fminf(n, 127.f);
          Pl[w][mi][(q * 4 + r) * 40 + st * 16 + lm] = f2bf(n);
        }
      }
    __syncthreads();
    short8 ap[2];
#pragma unroll
    for (int mi = 0; mi < 2; mi++)
      ap[mi] = *(const short8*)(&Pl[w][mi][lm * 40 + q * 8]);
#pragma unroll
    for (int j = 0; j < 8; j++) {
      int d = j * 16 + lm;
      int vphys = q ^ ((d >> 1) & 3);
      short8 bv = *(const short8*)(Vs + d * 32 + vphys * 8);
#pragma unroll
      for (int mi = 0; mi < 2; mi++) accO[mi][j] = MFMA16(ap[mi], bv, accO[mi][j]);
    }
  }
  float osc = sp * sv;
#pragma unroll
  for (int mi = 0; mi < 2; mi++)
#pragma unroll
    for (int j = 0; j < 8; j++)
#pragma unroll
      for (int r = 0; r < 4; r++)
        attn[(size_t)(mb + mi * 16 + q * 4 + r) * DIM + h * HD + j * 16 + lm] =
            accO[mi][j][r] * osc;
}

// ---------------------------------------------------------------------------
// K5: out-proj: out[m,n] = sum_c O[m,c]*Wo[n,c] + bo[n]. Split-MFMA.
// Same pipelined structure as K1; A from pre-tiled Oh/Ol. Grid: (12, 16).
// ---------------------------------------------------------------------------
__global__ __launch_bounds__(256) void k_gemm_out(
    const unsigned short* __restrict__ Oh, const unsigned short* __restrict__ Ol,
    const float* __restrict__ Wo, const float* __restrict__ bo,
    float* __restrict__ out) {
  __shared__ __align__(16) unsigned short Ahs[3][4096], Als[3][4096];
  __shared__ __align__(16) unsigned short Bhs[2][4096], Bls[2][4096];
  int tid = threadIdx.x;
  // bijective XCD swizzle: 192 blocks = 8 x 24
  int L = blockIdx.x + 12 * blockIdx.y;
  int L2 = (L & 7) * 24 + (L >> 3);
  int by2 = L2 & 15, bx2 = L2 >> 4;
  int n0 = bx2 * 128, m0 = by2 * 128;
  int lane = tid & 63, w = tid >> 6;
  int wr = w >> 1, wc = w & 1, lm = lane & 15, q = lane >> 4;

  floatx4 acc[4][4];
#pragma unroll
  for (int i = 0; i < 4; i++)
#pragma unroll
    for (int j = 0; j < 4; j++) acc[i][j] = (floatx4){0.f, 0.f, 0.f, 0.f};

  int rowA = tid >> 2, c8 = tid & 3;
  const float* pB0 = Wo + (size_t)(n0 + rowA) * DIM + c8 * 8;
  const float* pB1 = pB0 + (size_t)64 * DIM;
  size_t tb = (size_t)by2 * 48 * 4096;
  int sidx0 = tid, sidx1 = 256 + tid;
  int phA = (q ^ ((lm >> 1) & 3)) * 8;
  int mrbase = wr * 64 + lm;
  unsigned short* Abh = &Ahs[0][0];
  unsigned short* Abl = &Als[0][0];
  unsigned short* Bbh = &Bhs[0][0];
  unsigned short* Bbl = &Bls[0][0];
  const unsigned short* XH_ = Oh;
  const unsigned short* XL_ = Ol;

  float4 wA0, wA1, wA2, wA3, wB0, wB1, wB2, wB3;
  wB0 = *(const float4*)(pB0);
  wB1 = *(const float4*)(pB0 + 4);
  wB2 = *(const float4*)(pB1);
  wB3 = *(const float4*)(pB1 + 4);
  async_cp16(XH_ + tb + sidx0 * 8, Abh + sidx0 * 8);
  async_cp16(XL_ + tb + sidx0 * 8, Abl + sidx0 * 8);
  async_cp16(XH_ + tb + sidx1 * 8, Abh + sidx1 * 8);
  async_cp16(XL_ + tb + sidx1 * 8, Abl + sidx1 * 8);
  async_cp16(XH_ + tb + 4096 + sidx0 * 8, Abh + 4096 + sidx0 * 8);
  async_cp16(XL_ + tb + 4096 + sidx0 * 8, Abl + 4096 + sidx0 * 8);
  async_cp16(XH_ + tb + 4096 + sidx1 * 8, Abh + 4096 + sidx1 * 8);
  async_cp16(XL_ + tb + 4096 + sidx1 * 8, Abl + 4096 + sidx1 * 8);
  wA0 = *(const float4*)(pB0 + 32);
  wA1 = *(const float4*)(pB0 + 36);
  wA2 = *(const float4*)(pB1 + 32);
  wA3 = *(const float4*)(pB1 + 36);
  SPLIT_B(0, wB0, wB1, wB2, wB3);
  asm volatile("s_waitcnt vmcnt(8) lgkmcnt(0)" ::: "memory");
  __builtin_amdgcn_s_barrier();
  __builtin_amdgcn_sched_barrier(0);

  int scur = 0;
  for (int p = 0; p < 23; ++p) {
    GSTEP(2 * p, scur, wA0, wA1, wA2, wA3, wB0, wB1, wB2, wB3);
    scur = (scur + 1 == 3) ? 0 : scur + 1;
    GSTEP(2 * p + 1, scur, wB0, wB1, wB2, wB3, wA0, wA1, wA2, wA3);
    scur = (scur + 1 == 3) ? 0 : scur + 1;
  }
  COMPUTE_TILE(1, 0);
  SPLIT_B(1, wA0, wA1, wA2, wA3);
  asm volatile("s_waitcnt lgkmcnt(0)" ::: "memory");
  __builtin_amdgcn_s_barrier();
  __builtin_amdgcn_sched_barrier(0);
  COMPUTE_TILE(2, 1);

#pragma unroll
  for (int j = 0; j < 4; j++) {
    int col = n0 + wc * 64 + j * 16 + lm;
    float bias = bo[col];
#pragma unroll
    for (int i = 0; i < 4; i++) {
      int row = m0 + wr * 64 + i * 16 + q * 4;
#pragma unroll
      for (int r = 0; r < 4; r++)
        out[(size_t)(row + r) * DIM + col] = acc[i][j][r] + bias;
    }
  }
}

// ---------------------------------------------------------------------------
extern "C" void kernel_launch(void* const* d_in, const int* in_sizes, int n_in,
                              void* d_out, int out_size, void* d_ws, size_t ws_size,
                              hipStream_t stream) {
  float* out = (float*)d_out;
  bool sizes_ok = (n_in >= 6) && in_sizes && in_sizes[0] == SEQ * DIM &&
                  in_sizes[1] == DIM * DIM && in_sizes[2] == DIM * DIM &&
                  in_sizes[3] == DIM * DIM && in_sizes[4] == DIM * DIM &&
                  in_sizes[5] == DIM && out_size == SEQ * DIM;
  if (!sizes_ok) {
    k_fill<<<(out_size + 255) / 256, 256, 0, stream>>>(out, out_size, 1.0f);
    return;
  }
  if (ws_size < 50528272) {
    k_fill<<<(out_size + 255) / 256, 256, 0, stream>>>(out, out_size, 2.0f);
    return;
  }

  const float* x  = (const float*)d_in[0];
  const float* Wq = (const float*)d_in[1];
  const float* Wk = (const float*)d_in[2];
  const float* Wv = (const float*)d_in[3];
  const float* Wo = (const float*)d_in[4];
  const float* bo = (const float*)d_in[5];
  char* ws = (char*)d_ws;

  // Workspace layout (peak < 50.53 MB):
  float* qf = (float*)(ws);                                // 12,582,912 B
  float* kf = (float*)(ws + 12582912);                     // 12,582,912 B
  float* vf = (float*)(ws + 25165824);                     // 12,582,912 B
  unsigned short* nq  = (unsigned short*)(ws + 25165824);  // aliases vf (dead)
  float* pstats = (float*)(ws + 31457280);                 // 1,572,864 B
  unsigned short* nvT = (unsigned short*)(ws + 37748736);  // 6,291,456 B
  unsigned short* nk  = (unsigned short*)(ws + 44040192);  // 6,291,456 B
  // X-split tiled planes live in the nvT/nk slots until quant kernels run:
  unsigned short* Xh = nvT;   // dead after k_gemm_qkv
  unsigned short* Xl = nk;    // dead after k_gemm_qkv
  // attn-output tiled planes reuse the same slots after k_attn:
  unsigned short* Oh = nvT;   // written by k_split_o (nvT dead after k_attn)
  unsigned short* Ol = nk;    // written by k_split_o (nk dead after k_attn)
  float* attn0 = qf;                                       // aliases qf (dead)
  float* attn1 = kf;                                       // aliases kf (dead)
  float* stats = (float*)(ws + 50331648);                  // 196,608 B
  unsigned int* scal = (unsigned int*)(ws + 50528256);     // 16 B

  hipMemsetAsync(scal, 0, 12, stream);
  hipMemsetAsync(scal + 3, 0x7f, 4, stream);  // minZ init ~3.39e38

  k_split_x<<<dim3(48, 16), 256, 0, stream>>>(x, Xh, Xl);
  k_gemm_qkv<<<dim3(12, 8, 3), 256, 0, stream>>>(Xh, Xl, Wq, Wk, Wv, qf, kf,
                                                 vf, scal, 0);
  k_gemm_qkv<<<dim3(12, 8, 3), 256, 0, stream>>>(Xh, Xl, Wq, Wk, Wv, qf, kf,
                                                 vf, scal, 8);
  k_quant_vT<<<dim3(SEQ / 64, HD / 64, NH), 256, 0, stream>>>(vf, scal, nvT);
  k_quant_qk<<<dim3((SEQ * DIM) / 1024, 2), 256, 0, stream>>>(qf, kf, scal, nq, nk);
  k_stats<<<dim3(8 * 16, NH), 256, 0, stream>>>(nq, nk, scal, pstats);
  k_merge<<<dim3(NH * SEQ / 256), 256, 0, stream>>>(pstats, stats, scal + 3);
  k_attn<<<dim3(2 * 16, NH), 256, 0, stream>>>(nq, nk, nvT, scal, scal + 3,
                                               stats, attn0, attn1);
  k_split_o<<<dim3(48, 16), 256, 0, stream>>>(attn0, attn1, Oh, Ol);
  k_gemm_out<<<dim3(12, 16), 256, 0, stream>>>(Oh, Ol, Wo, bo, out);
}

// Round 8
// 472.828 us; speedup vs baseline: 1.1565x; 1.1064x over previous
//
#include <hip/hip_runtime.h>
#include <stdint.h>

// B=1, L=2048, DIM=1536, H=12, HD=128. Inputs f32, output f32 (verified R6).
// R15 instrumentation verdict: k_stats = 111.6us (VALUBusy 41%, Mfma 4%) —
// libm expf (~20 instr, serial m/z chain) over 75M calls; k_attn pays the
// same tax. qkv m-split serialized (113+111 vs 195) — reverted.
// R16: (1) expf -> __expf (v_exp_f32 native, 2 instr) consistently in
// k_stats/k_attn/k_merge. Scores & maxes untouched (MFMA+fmax identical);
// exp rel-err 1ulp->~3ulp shifts rintf boundaries w.p. ~1e-6/element =>
// absmax shift <<1e-4 (headroom 1.65e-3). (2) k_gemm_qkv back to single
// 576-block dispatch (best measured form, R13).
#define SEQ 2048
#define DIM 1536
#define NH  12
#define HD  128
#define SCALEF 0.08838834764831845f  // 128^-0.5

typedef __attribute__((ext_vector_type(8))) short short8;
typedef __attribute__((ext_vector_type(4))) float floatx4;

#define MFMA16(a, b, c) __builtin_amdgcn_mfma_f32_16x16x32_bf16((a), (b), (c), 0, 0, 0)

__device__ __forceinline__ void async_cp16(const void* g, void* l) {
  __builtin_amdgcn_global_load_lds(
      (__attribute__((address_space(1))) unsigned int*)(g),
      (__attribute__((address_space(3))) unsigned int*)(l), 16, 0, 0);
}

__device__ __forceinline__ unsigned short f2bf(float f) {
  unsigned int u = __float_as_uint(f);
  u = (u + 0x7fff + ((u >> 16) & 1)) >> 16;  // RNE
  return (unsigned short)u;
}

// Split f32 -> hi (truncated bf16) + lo (RNE bf16 of residual).
__device__ __forceinline__ void split8v(const float* x, short8& h, short8& l) {
#pragma unroll
  for (int e = 0; e < 8; e++) {
    unsigned int u = __float_as_uint(x[e]);
    h[e] = (short)(u >> 16);
    float r = x[e] - __uint_as_float(u & 0xFFFF0000u);
    l[e] = (short)f2bf(r);
  }
}
__device__ __forceinline__ void split8(const float* g, short8& h, short8& l) {
  float4 f0 = *(const float4*)g, f1 = *(const float4*)(g + 4);
  float x[8] = {f0.x, f0.y, f0.z, f0.w, f1.x, f1.y, f1.z, f1.w};
  split8v(x, h, l);
}

__global__ __launch_bounds__(256) void k_fill(float* __restrict__ out, int n,
                                              float val) {
  int i = blockIdx.x * 256 + threadIdx.x;
  if (i < n) out[i] = val;
}

// ---------------------------------------------------------------------------
// K0a: pre-split X -> tiled bf16 planes. Tile (mb,ks) = 8KB contiguous,
// rows mb*128..+127 x k ks*32..+31, chunk-xor (p ^ (row>>1)&3) pre-applied.
// Grid: (48 ks, 16 mb).
// ---------------------------------------------------------------------------
__global__ __launch_bounds__(256) void k_split_x(
    const float* __restrict__ X, unsigned short* __restrict__ Xh,
    unsigned short* __restrict__ Xl) {
  int ks = blockIdx.x, mb = blockIdx.y, tid = threadIdx.x;
  size_t tb = ((size_t)mb * 48 + ks) * 4096;
#pragma unroll
  for (int i = 0; i < 2; i++) {
    int sidx = i * 256 + tid;
    int row = sidx >> 2, p = sidx & 3;
    int c = p ^ ((row >> 1) & 3);
    short8 h, l;
    split8(X + (size_t)(mb * 128 + row) * DIM + ks * 32 + c * 8, h, l);
    *(short8*)(Xh + tb + sidx * 8) = h;
    *(short8*)(Xl + tb + sidx * 8) = l;
  }
}

// ---------------------------------------------------------------------------
// K0b: pre-sum + split attn output -> tiled Oh/Ol (same layout as k_split_x).
// ---------------------------------------------------------------------------
__global__ __launch_bounds__(256) void k_split_o(
    const float* __restrict__ A0, const float* __restrict__ A1,
    unsigned short* __restrict__ Oh, unsigned short* __restrict__ Ol) {
  int ks = blockIdx.x, mb = blockIdx.y, tid = threadIdx.x;
  size_t tb = ((size_t)mb * 48 + ks) * 4096;
#pragma unroll
  for (int i = 0; i < 2; i++) {
    int sidx = i * 256 + tid;
    int row = sidx >> 2, p = sidx & 3;
    int c = p ^ ((row >> 1) & 3);
    size_t off = (size_t)(mb * 128 + row) * DIM + ks * 32 + c * 8;
    float4 x0 = *(const float4*)(A0 + off), x1 = *(const float4*)(A0 + off + 4);
    float4 y0 = *(const float4*)(A1 + off), y1 = *(const float4*)(A1 + off + 4);
    float xs[8] = {x0.x + y0.x, x0.y + y0.y, x0.z + y0.z, x0.w + y0.w,
                   x1.x + y1.x, x1.y + y1.y, x1.z + y1.z, x1.w + y1.w};
    short8 h, l;
    split8v(xs, h, l);
    *(short8*)(Oh + tb + sidx * 8) = h;
    *(short8*)(Ol + tb + sidx * 8) = l;
  }
}

// ---------------------------------------------------------------------------
// Pipelined split-MFMA GEMM step macros (shared by k_gemm_qkv / k_gemm_out).
// ---------------------------------------------------------------------------
#define COMPUTE_TILE(SA, SB)                                                  \
  {                                                                           \
    const unsigned short* Ah_ = Abh + (SA) * 4096;                            \
    const unsigned short* Al_ = Abl + (SA) * 4096;                            \
    const unsigned short* Bh_ = Bbh + (SB) * 4096;                            \
    const unsigned short* Bl_ = Bbl + (SB) * 4096;                            \
    short8 ah_[4], al_[4], bh_[4], bl_[4];                                    \
    _Pragma("unroll") for (int i_ = 0; i_ < 4; i_++) {                        \
      int off_ = (mrbase + i_ * 16) * 32 + phA;                               \
      ah_[i_] = *(const short8*)(Ah_ + off_);                                 \
      al_[i_] = *(const short8*)(Al_ + off_);                                 \
    }                                                                         \
    _Pragma("unroll") for (int j_ = 0; j_ < 4; j_++) {                        \
      int off_ = q * 1024 + (wc * 64 + j_ * 16 + lm) * 8;                     \
      bh_[j_] = *(const short8*)(Bh_ + off_);                                 \
      bl_[j_] = *(const short8*)(Bl_ + off_);                                 \
    }                                                                         \
    __builtin_amdgcn_s_setprio(1);                                            \
    _Pragma("unroll") for (int i_ = 0; i_ < 4; i_++)                          \
      _Pragma("unroll") for (int j_ = 0; j_ < 4; j_++) {                      \
        acc[i_][j_] = MFMA16(ah_[i_], bh_[j_], acc[i_][j_]);                  \
        acc[i_][j_] = MFMA16(ah_[i_], bl_[j_], acc[i_][j_]);                  \
        acc[i_][j_] = MFMA16(al_[i_], bh_[j_], acc[i_][j_]);                  \
      }                                                                       \
    __builtin_amdgcn_s_setprio(0);                                            \
  }

#define SPLIT_B(SB, S0x, S1x, S2x, S3x)                                       \
  {                                                                           \
    unsigned short* BhN_ = Bbh + (SB) * 4096;                                 \
    unsigned short* BlN_ = Bbl + (SB) * 4096;                                 \
    short8 h_, l_;                                                            \
    {                                                                         \
      float xs_[8] = {S0x.x, S0x.y, S0x.z, S0x.w,                             \
                      S1x.x, S1x.y, S1x.z, S1x.w};                            \
      split8v(xs_, h_, l_);                                                   \
      *(short8*)(BhN_ + c8 * 1024 + rowA * 8) = h_;                           \
      *(short8*)(BlN_ + c8 * 1024 + rowA * 8) = l_;                           \
    }                                                                         \
    {                                                                         \
      float xs_[8] = {S2x.x, S2x.y, S2x.z, S2x.w,                             \
                      S3x.x, S3x.y, S3x.z, S3x.w};                            \
      split8v(xs_, h_, l_);                                                   \
      *(short8*)(BhN_ + c8 * 1024 + (64 + rowA) * 8) = h_;                    \
      *(short8*)(BlN_ + c8 * 1024 + (64 + rowA) * 8) = l_;                    \
    }                                                                         \
  }

#define GSTEP(T, SCUR, S0x, S1x, S2x, S3x, L0x, L1x, L2x, L3x)                \
  {                                                                           \
    const int t_ = (T), sc_ = (SCUR);                                         \
    const int sn_ = sc_ >= 1 ? sc_ - 1 : 2; /* (sc_+2)%3 */                   \
    size_t tn_ = tb + (size_t)(t_ + 2) * 4096;                                \
    async_cp16(XH_ + tn_ + sidx0 * 8, Abh + sn_ * 4096 + sidx0 * 8);          \
    async_cp16(XL_ + tn_ + sidx0 * 8, Abl + sn_ * 4096 + sidx0 * 8);          \
    async_cp16(XH_ + tn_ + sidx1 * 8, Abh + sn_ * 4096 + sidx1 * 8);          \
    async_cp16(XL_ + tn_ + sidx1 * 8, Abl + sn_ * 4096 + sidx1 * 8);          \
    {                                                                         \
      int kn_ = (t_ + 2) * 32;                                                \
      L0x = *(const float4*)(pB0 + kn_);                                      \
      L1x = *(const float4*)(pB0 + kn_ + 4);                                  \
      L2x = *(const float4*)(pB1 + kn_);                                      \
      L3x = *(const float4*)(pB1 + kn_ + 4);                                  \
    }                                                                         \
    COMPUTE_TILE(sc_, (t_) & 1);                                              \
    SPLIT_B((t_ + 1) & 1, S0x, S1x, S2x, S3x);                                \
    asm volatile("s_waitcnt vmcnt(8) lgkmcnt(0)" ::: "memory");               \
    __builtin_amdgcn_s_barrier();                                             \
    __builtin_amdgcn_sched_barrier(0);                                        \
  }

// ---------------------------------------------------------------------------
// K1: QKV projections: C[m,n] = sum_c X[m,c]*W[n,c]. Split-MFMA, 128x128
// tile, 3-deep A pipeline + W double-reg + counted vmcnt. Grid: (12,16,3).
// ---------------------------------------------------------------------------
__global__ __launch_bounds__(256) void k_gemm_qkv(
    const unsigned short* __restrict__ Xh, const unsigned short* __restrict__ Xl,
    const float* __restrict__ Wq, const float* __restrict__ Wk,
    const float* __restrict__ Wv, float* __restrict__ qf,
    float* __restrict__ kf, float* __restrict__ vf,
    unsigned int* __restrict__ scal) {
  __shared__ __align__(16) unsigned short Ahs[3][4096], Als[3][4096];
  __shared__ __align__(16) unsigned short Bhs[2][4096], Bls[2][4096];
  int tid = threadIdx.x;
  // bijective XCD swizzle: 576 blocks = 8 XCDs x 72.
  int L = blockIdx.x + 12 * blockIdx.y + 192 * blockIdx.z;
  int L2 = (L & 7) * 72 + (L >> 3);
  int by2 = L2 & 15, rest = L2 >> 4;
  int bx2 = rest % 12, z = rest / 12;
  const float* W = (z == 0) ? Wq : (z == 1) ? Wk : Wv;
  float* C = (z == 0) ? qf : (z == 1) ? kf : vf;
  int n0 = bx2 * 128, m0 = by2 * 128;
  int lane = tid & 63, w = tid >> 6;
  int wr = w >> 1, wc = w & 1, lm = lane & 15, q = lane >> 4;

  floatx4 acc[4][4];
#pragma unroll
  for (int i = 0; i < 4; i++)
#pragma unroll
    for (int j = 0; j < 4; j++) acc[i][j] = (floatx4){0.f, 0.f, 0.f, 0.f};

  int rowA = tid >> 2, c8 = tid & 3;
  const float* pB0 = W + (size_t)(n0 + rowA) * DIM + c8 * 8;
  const float* pB1 = pB0 + (size_t)64 * DIM;
  size_t tb = (size_t)by2 * 48 * 4096;
  int sidx0 = tid, sidx1 = 256 + tid;
  int phA = (q ^ ((lm >> 1) & 3)) * 8;
  int mrbase = wr * 64 + lm;
  unsigned short* Abh = &Ahs[0][0];
  unsigned short* Abl = &Als[0][0];
  unsigned short* Bbh = &Bhs[0][0];
  unsigned short* Bbl = &Bls[0][0];
  const unsigned short* XH_ = Xh;
  const unsigned short* XL_ = Xl;

  float4 wA0, wA1, wA2, wA3, wB0, wB1, wB2, wB3;
  // prologue: W(0) -> wB (split now), A(0)->slot0, A(1)->slot1, W(1) -> wA.
  wB0 = *(const float4*)(pB0);
  wB1 = *(const float4*)(pB0 + 4);
  wB2 = *(const float4*)(pB1);
  wB3 = *(const float4*)(pB1 + 4);
  async_cp16(XH_ + tb + sidx0 * 8, Abh + sidx0 * 8);
  async_cp16(XL_ + tb + sidx0 * 8, Abl + sidx0 * 8);
  async_cp16(XH_ + tb + sidx1 * 8, Abh + sidx1 * 8);
  async_cp16(XL_ + tb + sidx1 * 8, Abl + sidx1 * 8);
  async_cp16(XH_ + tb + 4096 + sidx0 * 8, Abh + 4096 + sidx0 * 8);
  async_cp16(XL_ + tb + 4096 + sidx0 * 8, Abl + 4096 + sidx0 * 8);
  async_cp16(XH_ + tb + 4096 + sidx1 * 8, Abh + 4096 + sidx1 * 8);
  async_cp16(XL_ + tb + 4096 + sidx1 * 8, Abl + 4096 + sidx1 * 8);
  wA0 = *(const float4*)(pB0 + 32);
  wA1 = *(const float4*)(pB0 + 36);
  wA2 = *(const float4*)(pB1 + 32);
  wA3 = *(const float4*)(pB1 + 36);
  SPLIT_B(0, wB0, wB1, wB2, wB3);
  asm volatile("s_waitcnt vmcnt(8) lgkmcnt(0)" ::: "memory");
  __builtin_amdgcn_s_barrier();
  __builtin_amdgcn_sched_barrier(0);

  int scur = 0;
  for (int p = 0; p < 23; ++p) {
    GSTEP(2 * p, scur, wA0, wA1, wA2, wA3, wB0, wB1, wB2, wB3);
    scur = (scur + 1 == 3) ? 0 : scur + 1;
    GSTEP(2 * p + 1, scur, wB0, wB1, wB2, wB3, wA0, wA1, wA2, wA3);
    scur = (scur + 1 == 3) ? 0 : scur + 1;
  }
  // t=46: A slot 1, B slot 0; split W(47) (in wA) -> B slot 1.
  COMPUTE_TILE(1, 0);
  SPLIT_B(1, wA0, wA1, wA2, wA3);
  asm volatile("s_waitcnt lgkmcnt(0)" ::: "memory");
  __builtin_amdgcn_s_barrier();
  __builtin_amdgcn_sched_barrier(0);
  // t=47: A slot 2, B slot 1.
  COMPUTE_TILE(2, 1);

  float am = 0.f;
#pragma unroll
  for (int i = 0; i < 4; i++) {
    int row = m0 + wr * 64 + i * 16 + q * 4;
#pragma unroll
    for (int j = 0; j < 4; j++) {
      int col = n0 + wc * 64 + j * 16 + lm;
#pragma unroll
      for (int r = 0; r < 4; r++) {
        float v = acc[i][j][r];
        C[(size_t)(row + r) * DIM + col] = v;
        am = fmaxf(am, fabsf(v));
      }
    }
  }
#pragma unroll
  for (int mk = 32; mk >= 1; mk >>= 1) am = fmaxf(am, __shfl_xor(am, mk, 64));
  if (lane == 0) atomicMax(&scal[z], __float_as_uint(am));
}

// ---------------------------------------------------------------------------
// K2a: quantize + transpose V -> nvT[h][d][k] (bf16 integer values).
// ---------------------------------------------------------------------------
__global__ __launch_bounds__(256) void k_quant_vT(
    const float* __restrict__ vf, const unsigned int* __restrict__ scal,
    unsigned short* __restrict__ nvT) {
  __shared__ float T[64 * 65];
  int h = blockIdx.z, d0 = blockIdx.y * 64, k0 = blockIdx.x * 64;
  float s = __uint_as_float(scal[2]) / 127.f;
  int t = threadIdx.x;
#pragma unroll
  for (int i = 0; i < 16; i++) {
    int idx = i * 256 + t;
    int r = idx >> 6, c = idx & 63;
    float v = vf[(size_t)(k0 + r) * DIM + h * HD + d0 + c];
    T[r * 65 + c] = fminf(fmaxf(rintf(v / s), -128.f), 127.f);
  }
  __syncthreads();
#pragma unroll
  for (int i = 0; i < 16; i++) {
    int idx = i * 256 + t;
    int d = idx >> 6, r = idx & 63;
    nvT[(size_t)(h * HD + d0 + d) * SEQ + k0 + r] = f2bf(T[r * 65 + d]);
  }
}

// ---------------------------------------------------------------------------
// K2b: quantize q,k -> integer-valued bf16.
// ---------------------------------------------------------------------------
__global__ __launch_bounds__(256) void k_quant_qk(
    const float* __restrict__ qf, const float* __restrict__ kf,
    const unsigned int* __restrict__ scal,
    unsigned short* __restrict__ nq, unsigned short* __restrict__ nk) {
  int z = blockIdx.y;
  const float* src = z ? kf : qf;
  unsigned short* dst = z ? nk : nq;
  float s = __uint_as_float(scal[z]) / 127.f;
  size_t i = ((size_t)blockIdx.x * 256 + threadIdx.x) * 4;
  float4 v = *(const float4*)(src + i);
  ushort4 o;
  o.x = f2bf(fminf(fmaxf(rintf(v.x / s), -128.f), 127.f));
  o.y = f2bf(fminf(fmaxf(rintf(v.y / s), -128.f), 127.f));
  o.z = f2bf(fminf(fmaxf(rintf(v.z / s), -128.f), 127.f));
  o.w = f2bf(fminf(fmaxf(rintf(v.w / s), -128.f), 127.f));
  *(ushort4*)(dst + i) = o;
}

// ---------------------------------------------------------------------------
// K3: partial softmax stats, split-K x8, online per-lane (m,z), swizzled Ks.
// Grid: (8*16, NH). pstats[h][row][chunk][2]. __expf (native v_exp) for all
// exponentials — scores/maxes unchanged, only exp rounding differs (~3ulp).
// ---------------------------------------------------------------------------
__global__ __launch_bounds__(256) void k_stats(
    const unsigned short* __restrict__ nq, const unsigned short* __restrict__ nk,
    const unsigned int* __restrict__ scal, float* __restrict__ pstats) {
  __shared__ unsigned short Ks[32 * 128];
  int h = blockIdx.y, tid = threadIdx.x, lane = tid & 63, w = tid >> 6;
  int lm = lane & 15, q = lane >> 4;
  int qb = blockIdx.x & 15, chunk = blockIdx.x >> 4;
  int mb = qb * 128 + w * 32;
  int kbase = chunk * 256;
  float f = (__uint_as_float(scal[0]) / 127.f) *
            (__uint_as_float(scal[1]) / 127.f) * SCALEF;

  short8 aq[2][4];
#pragma unroll
  for (int mi = 0; mi < 2; mi++) {
    const unsigned short* qb_p =
        nq + (size_t)(mb + mi * 16 + lm) * DIM + h * HD + q * 8;
#pragma unroll
    for (int cc = 0; cc < 4; cc++) aq[mi][cc] = *(const short8*)(qb_p + cc * 32);
  }

  float m[2][4], zz[2][4];
#pragma unroll
  for (int mi = 0; mi < 2; mi++)
#pragma unroll
    for (int r = 0; r < 4; r++) { m[mi][r] = -3.0e38f; zz[mi][r] = 0.f; }

  for (int kt = kbase; kt < kbase + 256; kt += 32) {
    __syncthreads();
#pragma unroll
    for (int i = 0; i < 2; i++) {
      int ch = i * 256 + tid;
      int krow = ch >> 4;
      int gcol = (ch & 15) ^ (krow & 7);  // xor-swizzle source column
      async_cp16(nk + (size_t)(kt + krow) * DIM + h * HD + gcol * 8,
                 Ks + ch * 8);
    }
    __syncthreads();
    short8 bk[2][4];
#pragma unroll
    for (int st = 0; st < 2; st++)
#pragma unroll
      for (int cc = 0; cc < 4; cc++) {
        int phys = (cc * 4 + q) ^ (lm & 7);
        bk[st][cc] = *(const short8*)(Ks + (st * 16 + lm) * 128 + phys * 8);
      }
#pragma unroll
    for (int mi = 0; mi < 2; mi++) {
      floatx4 a0 = (floatx4){0.f, 0.f, 0.f, 0.f};
      floatx4 a1 = (floatx4){0.f, 0.f, 0.f, 0.f};
#pragma unroll
      for (int cc = 0; cc < 4; cc++) {
        a0 = MFMA16(aq[mi][cc], bk[0][cc], a0);
        a1 = MFMA16(aq[mi][cc], bk[1][cc], a1);
      }
#pragma unroll
      for (int r = 0; r < 4; r++) {
        float s0 = a0[r] * f, s1 = a1[r] * f;
        float nm = fmaxf(m[mi][r], fmaxf(s0, s1));
        zz[mi][r] = zz[mi][r] * __expf(m[mi][r] - nm) + __expf(s0 - nm) +
                    __expf(s1 - nm);
        m[mi][r] = nm;
      }
    }
  }
  // merge (m,z) across the 16 lanes sharing each row
#pragma unroll
  for (int mk = 1; mk < 16; mk <<= 1)
#pragma unroll
    for (int mi = 0; mi < 2; mi++)
#pragma unroll
      for (int r = 0; r < 4; r++) {
        float om = __shfl_xor(m[mi][r], mk, 64);
        float oz = __shfl_xor(zz[mi][r], mk, 64);
        float nm = fmaxf(m[mi][r], om);
        zz[mi][r] = zz[mi][r] * __expf(m[mi][r] - nm) + oz * __expf(om - nm);
        m[mi][r] = nm;
      }
  if (lm == 0) {
#pragma unroll
    for (int mi = 0; mi < 2; mi++)
#pragma unroll
      for (int r = 0; r < 4; r++) {
        int row = mb + mi * 16 + q * 4 + r;
        float* p = pstats + (((size_t)h * SEQ + row) * 8 + chunk) * 2;
        p[0] = m[mi][r];
        p[1] = zz[mi][r];
      }
  }
}

// ---------------------------------------------------------------------------
// K3b: merge 8 partial stats per row -> stats[h][row][2], global minZ.
// ---------------------------------------------------------------------------
__global__ __launch_bounds__(256) void k_merge(
    const float* __restrict__ pstats, float* __restrict__ stats,
    unsigned int* __restrict__ minZ) {
  int idx = blockIdx.x * 256 + threadIdx.x;  // h*SEQ + row
  const float* p = pstats + (size_t)idx * 16;
  float M = -3.0e38f;
#pragma unroll
  for (int c = 0; c < 8; c++) M = fmaxf(M, p[c * 2]);
  float Z = 0.f;
#pragma unroll
  for (int c = 0; c < 8; c++) Z += p[c * 2 + 1] * __expf(p[c * 2] - M);
  stats[(size_t)idx * 2] = M;
  stats[(size_t)idx * 2 + 1] = Z;
  atomicMin(minZ, __float_as_uint(Z));
}

// ---------------------------------------------------------------------------
// K4: pass 2 — scores, quantize probs, PV. Split-K x2 -> partial O buffers.
// Grid: (2*16, NH). Swizzled Ks and Vs. __expf for P numerators (consistent
// with k_stats z).
// ---------------------------------------------------------------------------
__global__ __launch_bounds__(256) void k_attn(
    const unsigned short* __restrict__ nq, const unsigned short* __restrict__ nk,
    const unsigned short* __restrict__ nvT,
    const unsigned int* __restrict__ scal, const unsigned int* __restrict__ minZ,
    const float* __restrict__ stats, float* __restrict__ attn0,
    float* __restrict__ attn1) {
  __shared__ unsigned short Ks[32 * 128];
  __shared__ unsigned short Vs[128 * 32];
  __shared__ unsigned short Pl[4][2][16 * 40];
  int h = blockIdx.y, tid = threadIdx.x, lane = tid & 63, w = tid >> 6;
  int lm = lane & 15, q = lane >> 4;
  int qb = blockIdx.x & 15, chunk = blockIdx.x >> 4;
  int mb = qb * 128 + w * 32;
  float* attn = chunk ? attn1 : attn0;
  float sv = __uint_as_float(scal[2]) / 127.f;
  float f = (__uint_as_float(scal[0]) / 127.f) *
            (__uint_as_float(scal[1]) / 127.f) * SCALEF;
  float sp = (1.f / __uint_as_float(*minZ)) / 127.f;
  float inv_sp = 1.f / sp;

  short8 aq[2][4];
#pragma unroll
  for (int mi = 0; mi < 2; mi++) {
    const unsigned short* qb_p =
        nq + (size_t)(mb + mi * 16 + lm) * DIM + h * HD + q * 8;
#pragma unroll
    for (int cc = 0; cc < 4; cc++) aq[mi][cc] = *(const short8*)(qb_p + cc * 32);
  }
  float M[2][4], invZ[2][4];
#pragma unroll
  for (int mi = 0; mi < 2; mi++)
#pragma unroll
    for (int r = 0; r < 4; r++) {
      int row = mb + mi * 16 + q * 4 + r;
      M[mi][r] = stats[((size_t)h * SEQ + row) * 2];
      invZ[mi][r] = 1.f / stats[((size_t)h * SEQ + row) * 2 + 1];
    }
  floatx4 accO[2][8];
#pragma unroll
  for (int mi = 0; mi < 2; mi++)
#pragma unroll
    for (int j = 0; j < 8; j++) accO[mi][j] = (floatx4){0.f, 0.f, 0.f, 0.f};

  int kbase = chunk * 1024;
  for (int kt = kbase; kt < kbase + 1024; kt += 32) {
    __syncthreads();
#pragma unroll
    for (int i = 0; i < 2; i++) {
      int ch = i * 256 + tid;
      int krow = ch >> 4;
      int gcol = (ch & 15) ^ (krow & 7);
      async_cp16(nk + (size_t)(kt + krow) * DIM + h * HD + gcol * 8,
                 Ks + ch * 8);
      int d = ch >> 2;
      int vcol = (ch & 3) ^ ((d >> 1) & 3);
      async_cp16(nvT + (size_t)(h * HD + d) * SEQ + kt + vcol * 8,
                 Vs + ch * 8);
    }
    __syncthreads();
    short8 bk[2][4];
#pragma unroll
    for (int st = 0; st < 2; st++)
#pragma unroll
      for (int cc = 0; cc < 4; cc++) {
        int phys = (cc * 4 + q) ^ (lm & 7);
        bk[st][cc] = *(const short8*)(Ks + (st * 16 + lm) * 128 + phys * 8);
      }
#pragma unroll
    for (int mi = 0; mi < 2; mi++)
#pragma unroll
      for (int st = 0; st < 2; st++) {
        floatx4 acc = (floatx4){0.f, 0.f, 0.f, 0.f};
#pragma unroll
        for (int cc = 0; cc < 4; cc++) acc = MFMA16(aq[mi][cc], bk[st][cc], acc);
#pragma unroll
        for (int r = 0; r < 4; r++) {
          float t = __expf(acc[r] * f - M[mi][r]);
          float n = rintf(t * invZ[mi][r] * inv_sp);
          n = fminf(n, 127.f);
          Pl[w][mi][(q * 4 + r) * 40 + st * 16 + lm] = f2bf(n);
        }
      }
    __syncthreads();
    short8 ap[2];
#pragma unroll
    for (int mi = 0; mi < 2; mi++)
      ap[mi] = *(const short8*)(&Pl[w][mi][lm * 40 + q * 8]);
#pragma unroll
    for (int j = 0; j < 8; j++) {
      int d = j * 16 + lm;
      int vphys = q ^ ((d >> 1) & 3);
      short8 bv = *(const short8*)(Vs + d * 32 + vphys * 8);
#pragma unroll
      for (int mi = 0; mi < 2; mi++) accO[mi][j] = MFMA16(ap[mi], bv, accO[mi][j]);
    }
  }
  float osc = sp * sv;
#pragma unroll
  for (int mi = 0; mi < 2; mi++)
#pragma unroll
    for (int j = 0; j < 8; j++)
#pragma unroll
      for (int r = 0; r < 4; r++)
        attn[(size_t)(mb + mi * 16 + q * 4 + r) * DIM + h * HD + j * 16 + lm] =
            accO[mi][j][r] * osc;
}

// ---------------------------------------------------------------------------
// K5: out-proj: out[m,n] = sum_c O[m,c]*Wo[n,c] + bo[n]. Split-MFMA.
// Same pipelined structure as K1; A from pre-tiled Oh/Ol. Grid: (12, 16).
// ---------------------------------------------------------------------------
__global__ __launch_bounds__(256) void k_gemm_out(
    const unsigned short* __restrict__ Oh, const unsigned short* __restrict__ Ol,
    const float* __restrict__ Wo, const float* __restrict__ bo,
    float* __restrict__ out) {
  __shared__ __align__(16) unsigned short Ahs[3][4096], Als[3][4096];
  __shared__ __align__(16) unsigned short Bhs[2][4096], Bls[2][4096];
  int tid = threadIdx.x;
  // bijective XCD swizzle: 192 blocks = 8 x 24
  int L = blockIdx.x + 12 * blockIdx.y;
  int L2 = (L & 7) * 24 + (L >> 3);
  int by2 = L2 & 15, bx2 = L2 >> 4;
  int n0 = bx2 * 128, m0 = by2 * 128;
  int lane = tid & 63, w = tid >> 6;
  int wr = w >> 1, wc = w & 1, lm = lane & 15, q = lane >> 4;

  floatx4 acc[4][4];
#pragma unroll
  for (int i = 0; i < 4; i++)
#pragma unroll
    for (int j = 0; j < 4; j++) acc[i][j] = (floatx4){0.f, 0.f, 0.f, 0.f};

  int rowA = tid >> 2, c8 = tid & 3;
  const float* pB0 = Wo + (size_t)(n0 + rowA) * DIM + c8 * 8;
  const float* pB1 = pB0 + (size_t)64 * DIM;
  size_t tb = (size_t)by2 * 48 * 4096;
  int sidx0 = tid, sidx1 = 256 + tid;
  int phA = (q ^ ((lm >> 1) & 3)) * 8;
  int mrbase = wr * 64 + lm;
  unsigned short* Abh = &Ahs[0][0];
  unsigned short* Abl = &Als[0][0];
  unsigned short* Bbh = &Bhs[0][0];
  unsigned short* Bbl = &Bls[0][0];
  const unsigned short* XH_ = Oh;
  const unsigned short* XL_ = Ol;

  float4 wA0, wA1, wA2, wA3, wB0, wB1, wB2, wB3;
  wB0 = *(const float4*)(pB0);
  wB1 = *(const float4*)(pB0 + 4);
  wB2 = *(const float4*)(pB1);
  wB3 = *(const float4*)(pB1 + 4);
  async_cp16(XH_ + tb + sidx0 * 8, Abh + sidx0 * 8);
  async_cp16(XL_ + tb + sidx0 * 8, Abl + sidx0 * 8);
  async_cp16(XH_ + tb + sidx1 * 8, Abh + sidx1 * 8);
  async_cp16(XL_ + tb + sidx1 * 8, Abl + sidx1 * 8);
  async_cp16(XH_ + tb + 4096 + sidx0 * 8, Abh + 4096 + sidx0 * 8);
  async_cp16(XL_ + tb + 4096 + sidx0 * 8, Abl + 4096 + sidx0 * 8);
  async_cp16(XH_ + tb + 4096 + sidx1 * 8, Abh + 4096 + sidx1 * 8);
  async_cp16(XL_ + tb + 4096 + sidx1 * 8, Abl + 4096 + sidx1 * 8);
  wA0 = *(const float4*)(pB0 + 32);
  wA1 = *(const float4*)(pB0 + 36);
  wA2 = *(const float4*)(pB1 + 32);
  wA3 = *(const float4*)(pB1 + 36);
  SPLIT_B(0, wB0, wB1, wB2, wB3);
  asm volatile("s_waitcnt vmcnt(8) lgkmcnt(0)" ::: "memory");
  __builtin_amdgcn_s_barrier();
  __builtin_amdgcn_sched_barrier(0);

  int scur = 0;
  for (int p = 0; p < 23; ++p) {
    GSTEP(2 * p, scur, wA0, wA1, wA2, wA3, wB0, wB1, wB2, wB3);
    scur = (scur + 1 == 3) ? 0 : scur + 1;
    GSTEP(2 * p + 1, scur, wB0, wB1, wB2, wB3, wA0, wA1, wA2, wA3);
    scur = (scur + 1 == 3) ? 0 : scur + 1;
  }
  COMPUTE_TILE(1, 0);
  SPLIT_B(1, wA0, wA1, wA2, wA3);
  asm volatile("s_waitcnt lgkmcnt(0)" ::: "memory");
  __builtin_amdgcn_s_barrier();
  __builtin_amdgcn_sched_barrier(0);
  COMPUTE_TILE(2, 1);

#pragma unroll
  for (int j = 0; j < 4; j++) {
    int col = n0 + wc * 64 + j * 16 + lm;
    float bias = bo[col];
#pragma unroll
    for (int i = 0; i < 4; i++) {
      int row = m0 + wr * 64 + i * 16 + q * 4;
#pragma unroll
      for (int r = 0; r < 4; r++)
        out[(size_t)(row + r) * DIM + col] = acc[i][j][r] + bias;
    }
  }
}

// ---------------------------------------------------------------------------
extern "C" void kernel_launch(void* const* d_in, const int* in_sizes, int n_in,
                              void* d_out, int out_size, void* d_ws, size_t ws_size,
                              hipStream_t stream) {
  float* out = (float*)d_out;
  bool sizes_ok = (n_in >= 6) && in_sizes && in_sizes[0] == SEQ * DIM &&
                  in_sizes[1] == DIM * DIM && in_sizes[2] == DIM * DIM &&
                  in_sizes[3] == DIM * DIM && in_sizes[4] == DIM * DIM &&
                  in_sizes[5] == DIM && out_size == SEQ * DIM;
  if (!sizes_ok) {
    k_fill<<<(out_size + 255) / 256, 256, 0, stream>>>(out, out_size, 1.0f);
    return;
  }
  if (ws_size < 50528272) {
    k_fill<<<(out_size + 255) / 256, 256, 0, stream>>>(out, out_size, 2.0f);
    return;
  }

  const float* x  = (const float*)d_in[0];
  const float* Wq = (const float*)d_in[1];
  const float* Wk = (const float*)d_in[2];
  const float* Wv = (const float*)d_in[3];
  const float* Wo = (const float*)d_in[4];
  const float* bo = (const float*)d_in[5];
  char* ws = (char*)d_ws;

  // Workspace layout (peak < 50.53 MB):
  float* qf = (float*)(ws);                                // 12,582,912 B
  float* kf = (float*)(ws + 12582912);                     // 12,582,912 B
  float* vf = (float*)(ws + 25165824);                     // 12,582,912 B
  unsigned short* nq  = (unsigned short*)(ws + 25165824);  // aliases vf (dead)
  float* pstats = (float*)(ws + 31457280);                 // 1,572,864 B
  unsigned short* nvT = (unsigned short*)(ws + 37748736);  // 6,291,456 B
  unsigned short* nk  = (unsigned short*)(ws + 44040192);  // 6,291,456 B
  // X-split tiled planes live in the nvT/nk slots until quant kernels run:
  unsigned short* Xh = nvT;   // dead after k_gemm_qkv
  unsigned short* Xl = nk;    // dead after k_gemm_qkv
  // attn-output tiled planes reuse the same slots after k_attn:
  unsigned short* Oh = nvT;   // written by k_split_o (nvT dead after k_attn)
  unsigned short* Ol = nk;    // written by k_split_o (nk dead after k_attn)
  float* attn0 = qf;                                       // aliases qf (dead)
  float* attn1 = kf;                                       // aliases kf (dead)
  float* stats = (float*)(ws + 50331648);                  // 196,608 B
  unsigned int* scal = (unsigned int*)(ws + 50528256);     // 16 B

  hipMemsetAsync(scal, 0, 12, stream);
  hipMemsetAsync(scal + 3, 0x7f, 4, stream);  // minZ init ~3.39e38

  k_split_x<<<dim3(48, 16), 256, 0, stream>>>(x, Xh, Xl);
  k_gemm_qkv<<<dim3(12, 16, 3), 256, 0, stream>>>(Xh, Xl, Wq, Wk, Wv, qf, kf,
                                                  vf, scal);
  k_quant_vT<<<dim3(SEQ / 64, HD / 64, NH), 256, 0, stream>>>(vf, scal, nvT);
  k_quant_qk<<<dim3((SEQ * DIM) / 1024, 2), 256, 0, stream>>>(qf, kf, scal, nq, nk);
  k_stats<<<dim3(8 * 16, NH), 256, 0, stream>>>(nq, nk, scal, pstats);
  k_merge<<<dim3(NH * SEQ / 256), 256, 0, stream>>>(pstats, stats, scal + 3);
  k_attn<<<dim3(2 * 16, NH), 256, 0, stream>>>(nq, nk, nvT, scal, scal + 3,
                                               stats, attn0, attn1);
  k_split_o<<<dim3(48, 16), 256, 0, stream>>>(attn0, attn1, Oh, Ol);
  k_gemm_out<<<dim3(12, 16), 256, 0, stream>>>(Oh, Ol, Wo, bo, out);
}